// Round 5
// baseline (4289.462 us; speedup 1.0000x reference)
//
#include <hip/hip_runtime.h>
#include <hip/hip_bf16.h>

// AttnDecoderRNN on MI355X.
// R1: transposed gate staging, G prefetch, vectorized elementwise.
// R2: 256-VGPR budget + B-fragment reg double-buffer (798 us/layer).
// R3: 4-WG Whh-in-reg attempt — FAILED: compiler rematerialized weight
//     loads (VGPR=56) + release/acquire cache maintenance every step.
// R4: 2-WG split (128 VGPR weights/lane), inline-asm register pin,
//     static breg indexing (uniform branch on g), split own/partner-K
//     MFMA phases to overlap exchange, nontemporal Hout, relaxed sc1
//     data path, per-wave bounded poll.

#define B_    1000
#define T_    101
#define E_    256
#define H_    256
#define BPAD  1008      // 63 * 16
#define MPAD  101824    // 1591 * 64  >= BPAD*T_ = 101808
#define NG    1024      // 4H
#define NSLICE 63

typedef __bf16 bf16;
typedef __bf16 bf16x8 __attribute__((ext_vector_type(8)));
typedef float  f32x4  __attribute__((ext_vector_type(4)));
typedef unsigned u32x4 __attribute__((ext_vector_type(4)));

__device__ __forceinline__ bf16 f2b(float f){
  unsigned u = __builtin_bit_cast(unsigned, f);
  u += 0x7FFFu + ((u >> 16) & 1u);               // RNE
  unsigned short h = (unsigned short)(u >> 16);
  return __builtin_bit_cast(bf16, h);
}
__device__ __forceinline__ float b2f(bf16 v){
  unsigned short s = __builtin_bit_cast(unsigned short, v);
  unsigned u = ((unsigned)s) << 16;
  return __builtin_bit_cast(float, u);
}
__device__ __forceinline__ float bflo(unsigned u){ return __builtin_bit_cast(float, u << 16); }
__device__ __forceinline__ float bfhi(unsigned u){ return __builtin_bit_cast(float, u & 0xffff0000u); }
__device__ __forceinline__ unsigned packbf(float a, float b){
  unsigned ua = __builtin_bit_cast(unsigned, a);
  ua += 0x7FFFu + ((ua >> 16) & 1u);
  unsigned ub = __builtin_bit_cast(unsigned, b);
  ub += 0x7FFFu + ((ub >> 16) & 1u);
  return (ua >> 16) | (ub & 0xffff0000u);
}
__device__ __forceinline__ float sigm(float x){ return 1.f/(1.f + __expf(-x)); }
__device__ __forceinline__ float tanh_(float x){ return 2.f/(1.f + __expf(-2.f*x)) - 1.f; }

// ---- pack W[N][K] f32 -> Bp[K/32][N][32] bf16 (MFMA B-fragment order) ----
__global__ void pack_bT(const float* __restrict__ src, bf16* __restrict__ dst,
                        int N, int K)
{
  const long batch = blockIdx.y;
  src += batch * (long)N * K;
  dst += batch * (long)(K/32) * N * 32;
  const int tid = blockIdx.x * blockDim.x + threadIdx.x;
  const int total = (K/32) * N * 4;
  if (tid >= total) return;
  const int kkc = tid & 3;
  const int rem = tid >> 2;
  const int n = rem % N;
  const int q = rem / N;
  const float* s = src + (long)n*K + q*32 + kkc*8;
  bf16x8 v;
  #pragma unroll
  for (int e=0;e<8;e++) v[e] = f2b(s[e]);
  *reinterpret_cast<bf16x8*>(dst + ((long)q*N + n)*32 + kkc*8) = v;
}

// ---- f32 transpose: dst[k][j] = src[j][k], src is [N][K] ----
__global__ void tr_f32(const float* __restrict__ src, float* __restrict__ dst,
                       int N, int K)
{
  const int id = blockIdx.x * blockDim.x + threadIdx.x;
  if (id >= N*K) return;
  const int k = id / N, j = id % N;
  dst[(long)k*N + j] = src[(long)j*K + k];
}

__global__ void bias_sum(const float* __restrict__ a, const float* __restrict__ b,
                         float* __restrict__ o, int n)
{
  const int i = blockIdx.x * blockDim.x + threadIdx.x;
  if (i < n) o[i] = a[i] + b[i];
}

// ---- embedding gather -> x bf16 [MPAD][256], zeros for pad rows ----
__global__ void embed_k(const int* __restrict__ ids, const float* __restrict__ emb,
                        bf16* __restrict__ x)
{
  const int tid = blockIdx.x * blockDim.x + threadIdx.x;   // MPAD*32 exact
  const int m = tid >> 5;
  const int c = (tid & 31) << 3;
  bf16x8 v;
  if (m < B_*T_) {
    const int id = ids[m];
    const float* e = emb + (long)id*E_ + c;
    #pragma unroll
    for (int j=0;j<8;j++) v[j] = f2b(e[j]);
  } else {
    #pragma unroll
    for (int j=0;j<8;j++) v[j] = f2b(0.f);
  }
  *reinterpret_cast<bf16x8*>(x + (long)m*256 + c) = v;
}

// ---- gates GEMM: G[m][1024] = A[m][256] @ Bp + bias, bf16 out ----
__launch_bounds__(512)
__global__ void gemm_gates(const bf16* __restrict__ A, const bf16* __restrict__ Bp,
                           const float* __restrict__ bias, bf16* __restrict__ Gout)
{
  __shared__ __align__(16) bf16 smem[17408];   // A: 64x264 ; epilogue stage: 8 x 16x136
  const int m0 = blockIdx.x * 64;
  const int tid = threadIdx.x;
  const int wave = tid >> 6;
  const int lane = tid & 63;
  const int l16 = lane & 15, lg = lane >> 4;

  for (int i = tid; i < 2048; i += 512){
    const int r = i >> 5, cc = (i & 31) << 3;
    *reinterpret_cast<bf16x8*>(&smem[r*264 + cc]) =
      *reinterpret_cast<const bf16x8*>(A + (long)(m0 + r)*256 + cc);
  }
  __syncthreads();

  f32x4 acc[4][8];
  #pragma unroll
  for (int ms=0; ms<4; ++ms)
    #pragma unroll
    for (int ns=0; ns<8; ++ns) acc[ms][ns] = f32x4{0.f,0.f,0.f,0.f};

  const bf16* bb = Bp + ((long)(wave*128 + l16) * 32 + lg*8);
  #pragma unroll 2
  for (int q=0; q<8; ++q){
    bf16x8 af[4];
    #pragma unroll
    for (int ms=0; ms<4; ++ms)
      af[ms] = *reinterpret_cast<const bf16x8*>(&smem[(ms*16 + l16)*264 + q*32 + lg*8]);
    bf16x8 bfr[8];
    #pragma unroll
    for (int ns=0; ns<8; ++ns)
      bfr[ns] = *reinterpret_cast<const bf16x8*>(bb + ((long)q*NG + ns*16) * 32);
    #pragma unroll
    for (int ms=0; ms<4; ++ms)
      #pragma unroll
      for (int ns=0; ns<8; ++ns)
        acc[ms][ns] = __builtin_amdgcn_mfma_f32_16x16x32_bf16(af[ms], bfr[ns], acc[ms][ns], 0,0,0);
  }

  float bv[8];
  #pragma unroll
  for (int ns=0; ns<8; ++ns) bv[ns] = bias[wave*128 + ns*16 + l16];

  bf16* stage = smem + wave*2176;
  #pragma unroll
  for (int ms=0; ms<4; ++ms){
    __syncthreads();
    #pragma unroll
    for (int ns=0; ns<8; ++ns)
      #pragma unroll
      for (int r=0; r<4; ++r)
        stage[(lg*4 + r)*136 + ns*16 + l16] = f2b(acc[ms][ns][r] + bv[ns]);
    __syncthreads();
    const int row = lane >> 2, ch = lane & 3;
    bf16* gout = Gout + (long)(m0 + ms*16 + row)*NG + wave*128;
    #pragma unroll
    for (int cc2=0; cc2<4; ++cc2){
      const int chunk = ch + cc2*4;
      *reinterpret_cast<bf16x8*>(gout + chunk*8) =
        *reinterpret_cast<const bf16x8*>(&stage[row*136 + chunk*8]);
    }
  }
}

// ---- R4 persistent LSTM: 63 slices x 2 WGs, Whh half in VGPRs ----
// WG (s,g): batch rows [16s,16s+16), local gate-col j in [0,512) maps to
// global gate col (j>>7)*256 + g*128 + (j&127); owns h-cols [g*128,(g+1)*128).
#define HALF_MFMA_(QB) { \
  _Pragma("unroll") \
  for (int qq=0; qq<4; ++qq){ \
    bf16x8 a = *reinterpret_cast<const bf16x8*>(&hbuf[l16*264 + ((QB)+qq)*32 + lg*8]); \
    _Pragma("unroll") \
    for (int ns=0; ns<4; ++ns) \
      acc[ns] = __builtin_amdgcn_mfma_f32_16x16x32_bf16(a, \
                  __builtin_bit_cast(bf16x8, breg[((QB)+qq)*4+ns]), acc[ns], 0,0,0); \
  } }

__launch_bounds__(512, 2)
__global__ void lstm_layer2(const bf16* __restrict__ G, const bf16* __restrict__ Bp,
                            bf16* __restrict__ Hout, unsigned* __restrict__ hX,
                            unsigned* __restrict__ flags)
{
  __shared__ __align__(16) bf16 hbuf[16*264];    // full h (16 x 256), padded rows
  __shared__ float gstage[512*17];                // gate partials [local col][row]
  const int bid = blockIdx.x;
  const int s = bid >> 1;
  const int g = bid & 1;
  const int b0 = s * 16;
  const int tid = threadIdx.x;
  const int wave = tid >> 6, lane = tid & 63;
  const int l16 = lane & 15, lg = lane >> 4;

  // ---- Whh half -> registers (32 x u32x4 = 128 VGPR), pinned ----
  u32x4 breg[32];
  #pragma unroll
  for (int q=0;q<8;q++){
    #pragma unroll
    for (int ns=0;ns<4;ns++){
      const int j = wave*64 + ns*16 + l16;                 // local col
      const int gcol = ((j>>7)<<8) + g*128 + (j&127);      // global gate col
      breg[q*4+ns] = *reinterpret_cast<const u32x4*>(Bp + ((long)q*NG + gcol)*32 + lg*8);
    }
  }
  #pragma unroll
  for (int i=0;i<32;i++) asm volatile("" : "+v"(breg[i]));

  for (int i = tid; i < 16*264; i += 512) hbuf[i] = f2b(0.f);

  // elementwise mapping: thread -> (row, cols j2,j2+1 and +64)
  const int row = tid >> 5;            // 0..15
  const int k32 = tid & 31;
  const int j2  = k32 * 2;             // [0,64)
  float c0a=0.f, c0b=0.f, c1a=0.f, c1b=0.f;

  const long grow = (long)(b0 + row) * T_;
  const bf16* gptr = G + grow*NG + g*128 + j2;
  bf16*       hop  = Hout + grow*256 + g*128 + j2;

  unsigned* flag = flags + s*16;
  unsigned* hx0 = hX + (size_t)s*2048 + row*128 + g*64 + k32;
  unsigned* hx1 = hx0 + (size_t)NSLICE*2048;

  // partner reload mapping: wave covers 128 words (2 rows) of partner half
  const int pw   = wave*128 + lane*2;      // [0,1024)
  const int prow = pw >> 6;
  const int pwd  = pw & 63;
  const unsigned* prl0 = hX + (size_t)s*2048 + prow*128 + (1-g)*64 + pwd;
  const unsigned* prl1 = prl0 + (size_t)NSLICE*2048;
  bf16* hbw = &hbuf[prow*264 + (1-g)*128 + pwd*2];

  __syncthreads();

  // G prefetch t=0
  unsigned gpre[8];
  #pragma unroll
  for (int q=0;q<4;q++){
    gpre[q*2+0] = *reinterpret_cast<const unsigned*>(gptr + q*256);
    gpre[q*2+1] = *reinterpret_cast<const unsigned*>(gptr + q*256 + 64);
  }

  f32x4 acc[4];
  #pragma unroll
  for (int ns=0;ns<4;ns++) acc[ns] = f32x4{0.f,0.f,0.f,0.f};

  for (int t = 0; t < T_; ++t){
    // ---- MFMA phase A: partner-K of h_{t-1} (acc carries own-K of h_{t-1}) ----
    if (g == 0) { HALF_MFMA_(4) } else { HALF_MFMA_(0) }

    // ---- dump gate partials (transposed [col][17]), reset acc ----
    #pragma unroll
    for (int ns=0;ns<4;ns++){
      const int jj = wave*64 + ns*16 + l16;
      float* gc = &gstage[jj*17 + lg*4];
      gc[0]=acc[ns][0]; gc[1]=acc[ns][1]; gc[2]=acc[ns][2]; gc[3]=acc[ns][3];
      acc[ns] = f32x4{0.f,0.f,0.f,0.f};
    }
    __syncthreads();                                   // B1

    // ---- elementwise: 4 h-cols per thread (j2,j2+1, +64) ----
    const float* gs = &gstage[j2*17 + row];
    const float i0 = sigm (bflo(gpre[0]) + gs[0]);
    const float i1 = sigm (bfhi(gpre[0]) + gs[17]);
    const float f0 = sigm (bflo(gpre[2]) + gs[2176]);
    const float f1 = sigm (bfhi(gpre[2]) + gs[2176+17]);
    const float g0 = tanh_(bflo(gpre[4]) + gs[4352]);
    const float g1 = tanh_(bfhi(gpre[4]) + gs[4352+17]);
    const float o0 = sigm (bflo(gpre[6]) + gs[6528]);
    const float o1 = sigm (bfhi(gpre[6]) + gs[6528+17]);
    c0a = f0*c0a + i0*g0;
    c0b = f1*c0b + i1*g1;
    const unsigned hw0 = packbf(o0*tanh_(c0a), o1*tanh_(c0b));

    const float i2 = sigm (bflo(gpre[1]) + gs[1088]);
    const float i3 = sigm (bfhi(gpre[1]) + gs[1088+17]);
    const float f2 = sigm (bflo(gpre[3]) + gs[1088+2176]);
    const float f3 = sigm (bfhi(gpre[3]) + gs[1088+2176+17]);
    const float g2 = tanh_(bflo(gpre[5]) + gs[1088+4352]);
    const float g3 = tanh_(bfhi(gpre[5]) + gs[1088+4352+17]);
    const float o2 = sigm (bflo(gpre[7]) + gs[1088+6528]);
    const float o3 = sigm (bfhi(gpre[7]) + gs[1088+6528+17]);
    c1a = f2*c1a + i2*g2;
    c1b = f3*c1b + i3*g3;
    const unsigned hw1 = packbf(o2*tanh_(c1a), o3*tanh_(c1b));

    // own half -> hbuf; publish -> hX (LLC); Hout nontemporal
    *reinterpret_cast<unsigned*>(&hbuf[row*264 + g*128 + j2])      = hw0;
    *reinterpret_cast<unsigned*>(&hbuf[row*264 + g*128 + j2 + 64]) = hw1;
    unsigned* hx = (t & 1) ? hx1 : hx0;
    __hip_atomic_store(hx,      hw0, __ATOMIC_RELAXED, __HIP_MEMORY_SCOPE_AGENT);
    __hip_atomic_store(hx + 32, hw1, __ATOMIC_RELAXED, __HIP_MEMORY_SCOPE_AGENT);
    __builtin_nontemporal_store(hw0, reinterpret_cast<unsigned*>(hop + (long)t*256));
    __builtin_nontemporal_store(hw1, reinterpret_cast<unsigned*>(hop + (long)t*256 + 64));

    __syncthreads();                                   // B2: drains all stores
    if (tid == 0)
      __hip_atomic_fetch_add(flag, 1u, __ATOMIC_RELEASE, __HIP_MEMORY_SCOPE_AGENT);

    // ---- G prefetch t+1 (after barrier so nothing drains it early) ----
    if (t + 1 < T_){
      const bf16* gt = gptr + (long)(t+1)*NG;
      #pragma unroll
      for (int q=0;q<4;q++){
        gpre[q*2+0] = *reinterpret_cast<const unsigned*>(gt + q*256);
        gpre[q*2+1] = *reinterpret_cast<const unsigned*>(gt + q*256 + 64);
      }
    }

    // ---- MFMA phase B: own-K of h_t (overlaps partner's publish) ----
    if (g == 0) { HALF_MFMA_(0) } else { HALF_MFMA_(4) }

    // ---- wait partner, reload its half of h_t ----
    {
      const unsigned tgt = 2u*(t+1);
      if (lane == 0){
        int guard = 0;
        while (__hip_atomic_load(flag, __ATOMIC_ACQUIRE, __HIP_MEMORY_SCOPE_AGENT) < tgt
               && ++guard < 32768)
          __builtin_amdgcn_s_sleep(1);
      }
      asm volatile("" ::: "memory");
      __builtin_amdgcn_sched_barrier(0);
      const unsigned* prl = (t & 1) ? prl1 : prl0;
      const unsigned w0 = __hip_atomic_load(prl,   __ATOMIC_RELAXED, __HIP_MEMORY_SCOPE_AGENT);
      const unsigned w1 = __hip_atomic_load(prl+1, __ATOMIC_RELAXED, __HIP_MEMORY_SCOPE_AGENT);
      *reinterpret_cast<unsigned*>(hbw)     = w0;
      *reinterpret_cast<unsigned*>(hbw + 2) = w1;
    }
    __syncthreads();                                   // B3: hbuf ready
  }
}

// ---- fused attention GEMM + softmax + applied (w*x) + flat bf16 ----
__launch_bounds__(256)
__global__ void attn_applied(const bf16* __restrict__ H2, const bf16* __restrict__ Wap,
                             const float* __restrict__ battn, const int* __restrict__ ids,
                             const float* __restrict__ emb, float* __restrict__ applied,
                             bf16* __restrict__ flat)
{
  __shared__ __align__(16) bf16 albuf[32*264];
  __shared__ float sbuf[32*257];
  const int mt = blockIdx.x, t = blockIdx.y;
  const int b0 = mt*32;
  const int tid = threadIdx.x;
  const int wave = tid >> 6, lane = tid & 63;
  const int l16 = lane & 15, lg = lane >> 4;

  for (int i = tid; i < 1024; i += 256){
    const int r = i >> 5, cc = (i & 31) << 3;
    const int b = b0 + r;
    bf16x8 v;
    if (b < B_) v = *reinterpret_cast<const bf16x8*>(H2 + ((long)b*T_ + t)*256 + cc);
    else { 
      #pragma unroll
      for (int j=0;j<8;j++) v[j] = f2b(0.f);
    }
    *reinterpret_cast<bf16x8*>(&albuf[r*264 + cc]) = v;
  }
  __syncthreads();

  f32x4 acc[2][4];
  #pragma unroll
  for (int ms=0; ms<2; ++ms)
    #pragma unroll
    for (int ns=0; ns<4; ++ns) acc[ms][ns] = f32x4{0.f,0.f,0.f,0.f};

  const bf16* bb = Wap + (long)t*65536 + ((long)(wave*64 + l16) * 32 + lg*8);
  #pragma unroll 2
  for (int q=0; q<8; ++q){
    bf16x8 a0 = *reinterpret_cast<const bf16x8*>(&albuf[l16*264 + q*32 + lg*8]);
    bf16x8 a1 = *reinterpret_cast<const bf16x8*>(&albuf[(16 + l16)*264 + q*32 + lg*8]);
    #pragma unroll
    for (int ns=0; ns<4; ++ns){
      bf16x8 b = *reinterpret_cast<const bf16x8*>(bb + ((long)q*256 + ns*16) * 32);
      acc[0][ns] = __builtin_amdgcn_mfma_f32_16x16x32_bf16(a0, b, acc[0][ns], 0,0,0);
      acc[1][ns] = __builtin_amdgcn_mfma_f32_16x16x32_bf16(a1, b, acc[1][ns], 0,0,0);
    }
  }
  float bv[4];
  #pragma unroll
  for (int ns=0; ns<4; ++ns) bv[ns] = battn[t*256 + wave*64 + ns*16 + l16];
  #pragma unroll
  for (int ms=0; ms<2; ++ms)
    #pragma unroll
    for (int ns=0; ns<4; ++ns)
      #pragma unroll
      for (int r=0; r<4; ++r)
        sbuf[(ms*16 + lg*4 + r)*257 + wave*64 + ns*16 + l16] = acc[ms][ns][r] + bv[ns];
  __syncthreads();

  const int row = tid >> 3, seg = tid & 7;
  const float* srow = &sbuf[row*257 + seg*32];
  float v[32];
  float mx = -1e30f;
  #pragma unroll
  for (int i=0;i<32;++i){ v[i] = srow[i]; mx = fmaxf(mx, v[i]); }
  #pragma unroll
  for (int off=1; off<8; off<<=1) mx = fmaxf(mx, __shfl_xor(mx, off));
  float s = 0.f;
  #pragma unroll
  for (int i=0;i<32;++i){ v[i] = __expf(v[i] - mx); s += v[i]; }
  #pragma unroll
  for (int off=1; off<8; off<<=1) s += __shfl_xor(s, off);
  const float inv = 1.f / s;
  const int b = b0 + row;
  if (b < B_){
    const int id = ids[b*T_ + t];
    const float* ex = emb + (long)id*256 + seg*32;
    float* ap = applied + ((long)b*T_ + t)*256 + seg*32;
    bf16* fp = flat + (long)b*25856 + t*256 + seg*32;
    #pragma unroll
    for (int i=0;i<32;++i){
      const float val = v[i]*inv*ex[i];
      ap[i] = val;
      fp[i] = f2b(val);
    }
  }
}

// ---- W1 GEMM: part[ks][m][n] = flat[m][ks-slice] @ W1p, K-split 8 ----
__launch_bounds__(512)
__global__ void gemm_mlp1(const bf16* __restrict__ A, const bf16* __restrict__ Bp,
                          float* __restrict__ part)
{
  const int m0 = blockIdx.x * 32;
  const int ks = blockIdx.y;
  const int tid = threadIdx.x;
  const int wave = tid >> 6, lane = tid & 63;
  const int l16 = lane & 15, lg = lane >> 4;
  f32x4 acc[2][4];
  #pragma unroll
  for (int ms=0; ms<2; ++ms)
    #pragma unroll
    for (int ns=0; ns<4; ++ns) acc[ms][ns] = f32x4{0.f,0.f,0.f,0.f};

  const bf16* arow0 = A + (long)(m0 + l16)*25856 + lg*8;
  const bf16* arow1 = A + (long)(m0 + 16 + l16)*25856 + lg*8;
  const bf16* bb = Bp + ((long)(wave*64 + l16) * 32 + lg*8);
  #pragma unroll 2
  for (int q = ks*101; q < ks*101 + 101; ++q){
    bf16x8 a0 = *reinterpret_cast<const bf16x8*>(arow0 + (long)q*32);
    bf16x8 a1 = *reinterpret_cast<const bf16x8*>(arow1 + (long)q*32);
    #pragma unroll
    for (int ns=0; ns<4; ++ns){
      bf16x8 b = *reinterpret_cast<const bf16x8*>(bb + ((long)q*512 + ns*16) * 32);
      acc[0][ns] = __builtin_amdgcn_mfma_f32_16x16x32_bf16(a0, b, acc[0][ns], 0,0,0);
      acc[1][ns] = __builtin_amdgcn_mfma_f32_16x16x32_bf16(a1, b, acc[1][ns], 0,0,0);
    }
  }
  #pragma unroll
  for (int ms=0; ms<2; ++ms)
    #pragma unroll
    for (int ns=0; ns<4; ++ns)
      #pragma unroll
      for (int r=0; r<4; ++r)
        part[((long)ks*1024 + m0 + ms*16 + lg*4 + r)*512 + wave*64 + ns*16 + l16] = acc[ms][ns][r];
}

__global__ void reduce_relu(const float* __restrict__ part, const float* __restrict__ b1,
                            float* __restrict__ d1)
{
  const int idx = blockIdx.x*256 + threadIdx.x;   // 524288 exact
  const int n = idx & 511, m = idx >> 9;
  float s = b1[n];
  #pragma unroll
  for (int k=0;k<8;k++) s += part[((long)k*1024 + m)*512 + n];
  d1[idx] = fmaxf(s, 0.f);
}

// ---- MLP layers 2..4 fused, one block per batch row ----
__launch_bounds__(128)
__global__ void mlp_tail(const float* __restrict__ d1, const float* __restrict__ W2T,
                         const float* __restrict__ b2, const float* __restrict__ W3T,
                         const float* __restrict__ b3, const float* __restrict__ Wout,
                         const float* __restrict__ bout, float* __restrict__ tag)
{
  __shared__ float r1[512];
  __shared__ float r2[128];
  __shared__ float r3[64];
  const int b = blockIdx.x;
  const int tid = threadIdx.x;
  for (int i = tid; i < 512; i += 128) r1[i] = d1[(long)b*512 + i];
  __syncthreads();
  float a = b2[tid];
  #pragma unroll 8
  for (int k=0;k<512;++k) a += W2T[k*128 + tid] * r1[k];
  r2[tid] = fmaxf(a, 0.f);
  __syncthreads();
  if (tid < 64){
    float a3 = b3[tid];
    #pragma unroll 8
    for (int k=0;k<128;++k) a3 += W3T[k*64 + tid] * r2[k];
    r3[tid] = fmaxf(a3, 0.f);
  }
  __syncthreads();
  if (tid < 64){
    float p = r3[tid] * Wout[tid];
    #pragma unroll
    for (int off=1; off<64; off<<=1) p += __shfl_xor(p, off);
    if (tid == 0) tag[b] = p + bout[0];
  }
}

extern "C" void kernel_launch(void* const* d_in, const int* in_sizes, int n_in,
                              void* d_out, int out_size, void* d_ws, size_t ws_size,
                              hipStream_t stream)
{
  const int*   ids   = (const int*)  d_in[0];
  const float* emb   = (const float*)d_in[1];
  const float* Wih1  = (const float*)d_in[2];
  const float* Whh1  = (const float*)d_in[3];
  const float* bih1  = (const float*)d_in[4];
  const float* bhh1  = (const float*)d_in[5];
  const float* Wih2  = (const float*)d_in[6];
  const float* Whh2  = (const float*)d_in[7];
  const float* bih2  = (const float*)d_in[8];
  const float* bhh2  = (const float*)d_in[9];
  const float* Wattn = (const float*)d_in[10];
  const float* battn = (const float*)d_in[11];
  const float* W1    = (const float*)d_in[12];
  const float* b1    = (const float*)d_in[13];
  const float* W2    = (const float*)d_in[14];
  const float* b2    = (const float*)d_in[15];
  const float* W3    = (const float*)d_in[16];
  const float* b3    = (const float*)d_in[17];
  const float* Wout  = (const float*)d_in[18];
  const float* bout  = (const float*)d_in[19];
  float* out = (float*)d_out;
  char*  ws  = (char*)d_ws;

  // workspace layout (bytes)
  constexpr size_t OW_IH1 = 0;
  constexpr size_t OW_HH1 = 524288;
  constexpr size_t OW_IH2 = 1048576;
  constexpr size_t OW_HH2 = 1572864;
  constexpr size_t OW_ATT = 2097152;     // 13,238,272
  constexpr size_t OW_W1  = 15335424;    // 26,476,544
  constexpr size_t OW_W2T = 41811968;
  constexpr size_t OW_W3T = 42074112;
  constexpr size_t OB1    = 42106880;
  constexpr size_t OB2    = 42110976;
  constexpr size_t OXH2   = 42115072;    // x bf16, later h2 (alias)
  constexpr size_t OG     = 94248960;    // gates (208.5MB); later flat+part alias
  constexpr size_t OFLAT  = OG;
  constexpr size_t OPART  = OG + 52953088;
  constexpr size_t OH1    = 302784512;
  constexpr size_t OD1    = 354918400;   // d1 (2MB) — dead during LSTMs:
  constexpr size_t OHX    = OD1;         //   hX: 2 parity x 63 x 8KB = 1,032,192
  constexpr size_t OFLG   = OD1 + 1032192; // flags: 2 layers x 4KB
  constexpr size_t NEED   = 357015552;
  if (ws_size < NEED) return;

  bf16*  pIH1 = (bf16*) (ws + OW_IH1);
  bf16*  pHH1 = (bf16*) (ws + OW_HH1);
  bf16*  pIH2 = (bf16*) (ws + OW_IH2);
  bf16*  pHH2 = (bf16*) (ws + OW_HH2);
  bf16*  pATT = (bf16*) (ws + OW_ATT);
  bf16*  pW1  = (bf16*) (ws + OW_W1);
  float* pW2T = (float*)(ws + OW_W2T);
  float* pW3T = (float*)(ws + OW_W3T);
  float* pB1  = (float*)(ws + OB1);
  float* pB2  = (float*)(ws + OB2);
  bf16*  pXH2 = (bf16*) (ws + OXH2);
  bf16*  pG   = (bf16*) (ws + OG);
  bf16*  pFLAT= (bf16*) (ws + OFLAT);
  float* pPART= (float*)(ws + OPART);
  bf16*  pH1  = (bf16*) (ws + OH1);
  float* pD1  = (float*)(ws + OD1);
  unsigned* pHX  = (unsigned*)(ws + OHX);
  unsigned* pFL1 = (unsigned*)(ws + OFLG);
  unsigned* pFL2 = (unsigned*)(ws + OFLG + 4096);

  // zero h1 pad tail (rows 101808..101823) before g2 GEMM reads it
  hipMemsetAsync(ws + OH1 + (size_t)101808*512, 0, (size_t)16*512, stream);
  // zero exchange flags for both LSTM layers (graph-replay safe)
  hipMemsetAsync(ws + OFLG, 0, 8192, stream);

  // weight packing
  pack_bT<<<dim3(128),        256, 0, stream>>>(Wih1,  pIH1, 1024, 256);
  pack_bT<<<dim3(128),        256, 0, stream>>>(Whh1,  pHH1, 1024, 256);
  pack_bT<<<dim3(128),        256, 0, stream>>>(Wih2,  pIH2, 1024, 256);
  pack_bT<<<dim3(128),        256, 0, stream>>>(Whh2,  pHH2, 1024, 256);
  pack_bT<<<dim3(32, 101),    256, 0, stream>>>(Wattn, pATT, 256,  256);
  pack_bT<<<dim3(6464),       256, 0, stream>>>(W1,    pW1,  512,  25856);
  tr_f32 <<<dim3(256),        256, 0, stream>>>(W2, pW2T, 128, 512);
  tr_f32 <<<dim3(32),         256, 0, stream>>>(W3, pW3T, 64, 128);
  bias_sum<<<dim3(4),         256, 0, stream>>>(bih1, bhh1, pB1, 1024);
  bias_sum<<<dim3(4),         256, 0, stream>>>(bih2, bhh2, pB2, 1024);

  // embed -> x bf16
  embed_k<<<dim3(12728), 256, 0, stream>>>(ids, emb, pXH2);

  // layer 1
  gemm_gates <<<dim3(1591), 512, 0, stream>>>(pXH2, pIH1, pB1, pG);
  lstm_layer2<<<dim3(126),  512, 0, stream>>>(pG, pHH1, pH1, pHX, pFL1);
  // layer 2
  gemm_gates <<<dim3(1591), 512, 0, stream>>>(pH1, pIH2, pB2, pG);
  lstm_layer2<<<dim3(126),  512, 0, stream>>>(pG, pHH2, pXH2, pHX, pFL2);

  // flat pad rows [1000,1024) zero (after gates buffer is dead)
  hipMemsetAsync(ws + OFLAT + (size_t)B_*25856*2, 0, (size_t)24*25856*2, stream);

  // attention + softmax + applied (writes d_out applied region + flat bf16)
  attn_applied<<<dim3(32, 101), 256, 0, stream>>>(pXH2, pATT, battn, ids, emb,
                                                  out + 1000, pFLAT);

  // MLP
  gemm_mlp1  <<<dim3(32, 8), 512, 0, stream>>>(pFLAT, pW1, pPART);
  reduce_relu<<<dim3(2048),  256, 0, stream>>>(pPART, b1, pD1);
  mlp_tail   <<<dim3(1000),  128, 0, stream>>>(pD1, pW2T, b2, pW3T, b3, Wout, bout, out);
}

// Round 6
// 2197.545 us; speedup vs baseline: 1.9519x; 1.9519x over previous
//
#include <hip/hip_runtime.h>
#include <hip/hip_bf16.h>

// AttnDecoderRNN on MI355X.
// R2: streaming LSTM, 63 WGs x 16 rows, reg double-buffer (798 us/layer).
// R3/R4: cross-WG register-resident Whh — FAILED (compiler spilled the
//        weight arrays to scratch; VGPR_Count 56/108 proved it).
// R5: hybrid residency, NO cross-WG exchange. Half of Whh (q=0..3) in 32
//     NAMED u32x4 vars loaded via inline-asm global_load_dwordx4 (cannot
//     be rematerialized or runtime-indexed); other half (q=4..7) streamed
//     with R2's single-buffer pattern. Stream volume per step halves.

#define B_    1000
#define T_    101
#define E_    256
#define H_    256
#define BPAD  1008      // 63 * 16
#define MPAD  101824    // 1591 * 64  >= BPAD*T_ = 101808
#define NG    1024      // 4H

typedef __bf16 bf16;
typedef __bf16 bf16x8 __attribute__((ext_vector_type(8)));
typedef float  f32x4  __attribute__((ext_vector_type(4)));
typedef unsigned u32x4 __attribute__((ext_vector_type(4)));

__device__ __forceinline__ bf16 f2b(float f){
  unsigned u = __builtin_bit_cast(unsigned, f);
  u += 0x7FFFu + ((u >> 16) & 1u);               // RNE
  unsigned short h = (unsigned short)(u >> 16);
  return __builtin_bit_cast(bf16, h);
}
__device__ __forceinline__ float b2f(bf16 v){
  unsigned short s = __builtin_bit_cast(unsigned short, v);
  unsigned u = ((unsigned)s) << 16;
  return __builtin_bit_cast(float, u);
}
__device__ __forceinline__ float sigm(float x){ return 1.f/(1.f + __expf(-x)); }
__device__ __forceinline__ float tanh_(float x){ return 2.f/(1.f + __expf(-2.f*x)) - 1.f; }

// asm 16B global load: result is an opaque register quad the compiler
// must keep (cannot re-execute the asm to rematerialize).
__device__ __forceinline__ u32x4 gload16(const bf16* p){
  u32x4 r;
  asm volatile("global_load_dwordx4 %0, %1, off" : "=v"(r) : "v"(p));
  return r;
}

// ---- pack W[N][K] f32 -> Bp[K/32][N][32] bf16 (MFMA B-fragment order) ----
__global__ void pack_bT(const float* __restrict__ src, bf16* __restrict__ dst,
                        int N, int K)
{
  const long batch = blockIdx.y;
  src += batch * (long)N * K;
  dst += batch * (long)(K/32) * N * 32;
  const int tid = blockIdx.x * blockDim.x + threadIdx.x;
  const int total = (K/32) * N * 4;
  if (tid >= total) return;
  const int kkc = tid & 3;
  const int rem = tid >> 2;
  const int n = rem % N;
  const int q = rem / N;
  const float* s = src + (long)n*K + q*32 + kkc*8;
  bf16x8 v;
  #pragma unroll
  for (int e=0;e<8;e++) v[e] = f2b(s[e]);
  *reinterpret_cast<bf16x8*>(dst + ((long)q*N + n)*32 + kkc*8) = v;
}

// ---- f32 transpose: dst[k][j] = src[j][k], src is [N][K] ----
__global__ void tr_f32(const float* __restrict__ src, float* __restrict__ dst,
                       int N, int K)
{
  const int id = blockIdx.x * blockDim.x + threadIdx.x;
  if (id >= N*K) return;
  const int k = id / N, j = id % N;
  dst[(long)k*N + j] = src[(long)j*K + k];
}

__global__ void bias_sum(const float* __restrict__ a, const float* __restrict__ b,
                         float* __restrict__ o, int n)
{
  const int i = blockIdx.x * blockDim.x + threadIdx.x;
  if (i < n) o[i] = a[i] + b[i];
}

// ---- embedding gather -> x bf16 [MPAD][256], zeros for pad rows ----
__global__ void embed_k(const int* __restrict__ ids, const float* __restrict__ emb,
                        bf16* __restrict__ x)
{
  const int tid = blockIdx.x * blockDim.x + threadIdx.x;   // MPAD*32 exact
  const int m = tid >> 5;
  const int c = (tid & 31) << 3;
  bf16x8 v;
  if (m < B_*T_) {
    const int id = ids[m];
    const float* e = emb + (long)id*E_ + c;
    #pragma unroll
    for (int j=0;j<8;j++) v[j] = f2b(e[j]);
  } else {
    #pragma unroll
    for (int j=0;j<8;j++) v[j] = f2b(0.f);
  }
  *reinterpret_cast<bf16x8*>(x + (long)m*256 + c) = v;
}

// ---- gates GEMM: G[m][1024] = A[m][256] @ Bp + bias, bf16 out ----
__launch_bounds__(512)
__global__ void gemm_gates(const bf16* __restrict__ A, const bf16* __restrict__ Bp,
                           const float* __restrict__ bias, bf16* __restrict__ Gout)
{
  __shared__ __align__(16) bf16 smem[17408];   // A: 64x264 ; epilogue stage: 8 x 16x136
  const int m0 = blockIdx.x * 64;
  const int tid = threadIdx.x;
  const int wave = tid >> 6;
  const int lane = tid & 63;
  const int l16 = lane & 15, lg = lane >> 4;

  for (int i = tid; i < 2048; i += 512){
    const int r = i >> 5, cc = (i & 31) << 3;
    *reinterpret_cast<bf16x8*>(&smem[r*264 + cc]) =
      *reinterpret_cast<const bf16x8*>(A + (long)(m0 + r)*256 + cc);
  }
  __syncthreads();

  f32x4 acc[4][8];
  #pragma unroll
  for (int ms=0; ms<4; ++ms)
    #pragma unroll
    for (int ns=0; ns<8; ++ns) acc[ms][ns] = f32x4{0.f,0.f,0.f,0.f};

  const bf16* bb = Bp + ((long)(wave*128 + l16) * 32 + lg*8);
  #pragma unroll 2
  for (int q=0; q<8; ++q){
    bf16x8 af[4];
    #pragma unroll
    for (int ms=0; ms<4; ++ms)
      af[ms] = *reinterpret_cast<const bf16x8*>(&smem[(ms*16 + l16)*264 + q*32 + lg*8]);
    bf16x8 bfr[8];
    #pragma unroll
    for (int ns=0; ns<8; ++ns)
      bfr[ns] = *reinterpret_cast<const bf16x8*>(bb + ((long)q*NG + ns*16) * 32);
    #pragma unroll
    for (int ms=0; ms<4; ++ms)
      #pragma unroll
      for (int ns=0; ns<8; ++ns)
        acc[ms][ns] = __builtin_amdgcn_mfma_f32_16x16x32_bf16(af[ms], bfr[ns], acc[ms][ns], 0,0,0);
  }

  float bv[8];
  #pragma unroll
  for (int ns=0; ns<8; ++ns) bv[ns] = bias[wave*128 + ns*16 + l16];

  bf16* stage = smem + wave*2176;
  #pragma unroll
  for (int ms=0; ms<4; ++ms){
    __syncthreads();
    #pragma unroll
    for (int ns=0; ns<8; ++ns)
      #pragma unroll
      for (int r=0; r<4; ++r)
        stage[(lg*4 + r)*136 + ns*16 + l16] = f2b(acc[ms][ns][r] + bv[ns]);
    __syncthreads();
    const int row = lane >> 2, ch = lane & 3;
    bf16* gout = Gout + (long)(m0 + ms*16 + row)*NG + wave*128;
    #pragma unroll
    for (int cc2=0; cc2<4; ++cc2){
      const int chunk = ch + cc2*4;
      *reinterpret_cast<bf16x8*>(gout + chunk*8) =
        *reinterpret_cast<const bf16x8*>(&stage[row*136 + chunk*8]);
    }
  }
}

// ---- R5 persistent LSTM: 63 WGs x 16 rows; Whh q=0..3 resident, q=4..7 streamed ----
#define MFW(a,w,acc) __builtin_amdgcn_mfma_f32_16x16x32_bf16((a), __builtin_bit_cast(bf16x8,(w)), (acc), 0,0,0)
#define MFS(a,s,acc) __builtin_amdgcn_mfma_f32_16x16x32_bf16((a), (s), (acc), 0,0,0)

#define MRESQ(q, W0,W1,W2,W3,W4,W5,W6,W7) { \
  bf16x8 a = *reinterpret_cast<const bf16x8*>(&hbuf[arow + (q)*32]); \
  acc0=MFW(a,W0,acc0); acc1=MFW(a,W1,acc1); acc2=MFW(a,W2,acc2); acc3=MFW(a,W3,acc3); \
  acc4=MFW(a,W4,acc4); acc5=MFW(a,W5,acc5); acc6=MFW(a,W6,acc6); acc7=MFW(a,W7,acc7); }

#define LOADSA(q) { \
  sA0 = *reinterpret_cast<const bf16x8*>(bb + ((long)(q)*NG +   0)*32); \
  sA1 = *reinterpret_cast<const bf16x8*>(bb + ((long)(q)*NG +  16)*32); \
  sA2 = *reinterpret_cast<const bf16x8*>(bb + ((long)(q)*NG +  32)*32); \
  sA3 = *reinterpret_cast<const bf16x8*>(bb + ((long)(q)*NG +  48)*32); \
  sA4 = *reinterpret_cast<const bf16x8*>(bb + ((long)(q)*NG +  64)*32); \
  sA5 = *reinterpret_cast<const bf16x8*>(bb + ((long)(q)*NG +  80)*32); \
  sA6 = *reinterpret_cast<const bf16x8*>(bb + ((long)(q)*NG +  96)*32); \
  sA7 = *reinterpret_cast<const bf16x8*>(bb + ((long)(q)*NG + 112)*32); }

#define MSTRQ(q) { \
  bf16x8 a = *reinterpret_cast<const bf16x8*>(&hbuf[arow + (q)*32]); \
  acc0=MFS(a,sA0,acc0); acc1=MFS(a,sA1,acc1); acc2=MFS(a,sA2,acc2); acc3=MFS(a,sA3,acc3); \
  acc4=MFS(a,sA4,acc4); acc5=MFS(a,sA5,acc5); acc6=MFS(a,sA6,acc6); acc7=MFS(a,sA7,acc7); }

#define DUMPNS(ns, accN) { \
  float* gc = &gbufT[(wave*128 + (ns)*16 + l16)*17 + lg*4]; \
  gc[0]=accN[0]; gc[1]=accN[1]; gc[2]=accN[2]; gc[3]=accN[3]; }

__launch_bounds__(512, 2)
__global__ void lstm_hybrid(const bf16* __restrict__ G, const bf16* __restrict__ Bp,
                            bf16* __restrict__ Hout)
{
  __shared__ __align__(16) bf16 hbuf[16*264];   // current h (16 x 256, padded)
  __shared__ float gbufT[1024*17];               // gate partials [col][row]
  const int b0 = blockIdx.x * 16;
  const int tid = threadIdx.x;
  const int wave = tid >> 6, lane = tid & 63;
  const int l16 = lane & 15, lg = lane >> 4;
  const int row8 = tid & 15;
  const int cg   = tid >> 4;
  const int arow = l16*264 + lg*8;

  const bf16* bb = Bp + ((long)(wave*128 + l16) * 32 + lg*8);

  // ---- resident half: q=0..3, 32 named asm-loaded register quads ----
  u32x4 w0  = gload16(bb + (0L*NG +   0)*32);
  u32x4 w1  = gload16(bb + (0L*NG +  16)*32);
  u32x4 w2  = gload16(bb + (0L*NG +  32)*32);
  u32x4 w3  = gload16(bb + (0L*NG +  48)*32);
  u32x4 w4  = gload16(bb + (0L*NG +  64)*32);
  u32x4 w5  = gload16(bb + (0L*NG +  80)*32);
  u32x4 w6  = gload16(bb + (0L*NG +  96)*32);
  u32x4 w7  = gload16(bb + (0L*NG + 112)*32);
  u32x4 w8  = gload16(bb + (1L*NG +   0)*32);
  u32x4 w9  = gload16(bb + (1L*NG +  16)*32);
  u32x4 w10 = gload16(bb + (1L*NG +  32)*32);
  u32x4 w11 = gload16(bb + (1L*NG +  48)*32);
  u32x4 w12 = gload16(bb + (1L*NG +  64)*32);
  u32x4 w13 = gload16(bb + (1L*NG +  80)*32);
  u32x4 w14 = gload16(bb + (1L*NG +  96)*32);
  u32x4 w15 = gload16(bb + (1L*NG + 112)*32);
  u32x4 w16 = gload16(bb + (2L*NG +   0)*32);
  u32x4 w17 = gload16(bb + (2L*NG +  16)*32);
  u32x4 w18 = gload16(bb + (2L*NG +  32)*32);
  u32x4 w19 = gload16(bb + (2L*NG +  48)*32);
  u32x4 w20 = gload16(bb + (2L*NG +  64)*32);
  u32x4 w21 = gload16(bb + (2L*NG +  80)*32);
  u32x4 w22 = gload16(bb + (2L*NG +  96)*32);
  u32x4 w23 = gload16(bb + (2L*NG + 112)*32);
  u32x4 w24 = gload16(bb + (3L*NG +   0)*32);
  u32x4 w25 = gload16(bb + (3L*NG +  16)*32);
  u32x4 w26 = gload16(bb + (3L*NG +  32)*32);
  u32x4 w27 = gload16(bb + (3L*NG +  48)*32);
  u32x4 w28 = gload16(bb + (3L*NG +  64)*32);
  u32x4 w29 = gload16(bb + (3L*NG +  80)*32);
  u32x4 w30 = gload16(bb + (3L*NG +  96)*32);
  u32x4 w31 = gload16(bb + (3L*NG + 112)*32);
  asm volatile("s_waitcnt vmcnt(0)" ::: "memory");
  __builtin_amdgcn_sched_barrier(0);

  for (int i = tid; i < 16*264; i += 512) hbuf[i] = f2b(0.f);
  float c[8];
  #pragma unroll
  for (int e=0;e<8;e++) c[e] = 0.f;

  const bf16* gbase = G + ((long)(b0 + row8)*T_)*NG + cg*8;
  bf16*       hout  = Hout + ((long)(b0 + row8)*T_)*256 + cg*8;
  __syncthreads();

  for (int t = 0; t < T_; ++t){
    // --- G prefetch (independent; consumed after B1) ---
    const bf16* gp = gbase + (long)t*NG;
    const bf16x8 gi = *reinterpret_cast<const bf16x8*>(gp);
    const bf16x8 gf = *reinterpret_cast<const bf16x8*>(gp + 256);
    const bf16x8 gg = *reinterpret_cast<const bf16x8*>(gp + 512);
    const bf16x8 go = *reinterpret_cast<const bf16x8*>(gp + 768);

    f32x4 acc0={0,0,0,0}, acc1={0,0,0,0}, acc2={0,0,0,0}, acc3={0,0,0,0};
    f32x4 acc4={0,0,0,0}, acc5={0,0,0,0}, acc6={0,0,0,0}, acc7={0,0,0,0};
    bf16x8 sA0,sA1,sA2,sA3,sA4,sA5,sA6,sA7;

    // issue q=4 stream loads, then resident MFMAs cover their latency
    LOADSA(4)
    MRESQ(0, w0,w1,w2,w3,w4,w5,w6,w7)
    MRESQ(1, w8,w9,w10,w11,w12,w13,w14,w15)
    MRESQ(2, w16,w17,w18,w19,w20,w21,w22,w23)
    MRESQ(3, w24,w25,w26,w27,w28,w29,w30,w31)
    MSTRQ(4)
    LOADSA(5)
    MSTRQ(5)
    LOADSA(6)
    MSTRQ(6)
    LOADSA(7)
    MSTRQ(7)

    // transposed gate staging [col][17]
    DUMPNS(0, acc0) DUMPNS(1, acc1) DUMPNS(2, acc2) DUMPNS(3, acc3)
    DUMPNS(4, acc4) DUMPNS(5, acc5) DUMPNS(6, acc6) DUMPNS(7, acc7)
    __syncthreads();   // B1: gates visible; hbuf reads done

    // --- elementwise: thread owns (row8, cols cg*8..cg*8+7) ---
    {
      bf16x8 hv;
      #pragma unroll
      for (int e=0;e<8;e++){
        const int hc = cg*8 + e;
        const float iv = sigm (b2f(gi[e]) + gbufT[(hc      )*17 + row8]);
        const float fv = sigm (b2f(gf[e]) + gbufT[(hc + 256)*17 + row8]);
        const float gv = tanh_(b2f(gg[e]) + gbufT[(hc + 512)*17 + row8]);
        const float ov = sigm (b2f(go[e]) + gbufT[(hc + 768)*17 + row8]);
        c[e] = fv*c[e] + iv*gv;
        hv[e] = f2b(ov * tanh_(c[e]));
      }
      *reinterpret_cast<bf16x8*>(&hbuf[row8*264 + cg*8]) = hv;
      *reinterpret_cast<bf16x8*>(hout + (long)t*256) = hv;
    }
    __syncthreads();   // B2: h updated before next step's reads
  }
}

// ---- fused attention GEMM + softmax + applied (w*x) + flat bf16 ----
__launch_bounds__(256)
__global__ void attn_applied(const bf16* __restrict__ H2, const bf16* __restrict__ Wap,
                             const float* __restrict__ battn, const int* __restrict__ ids,
                             const float* __restrict__ emb, float* __restrict__ applied,
                             bf16* __restrict__ flat)
{
  __shared__ __align__(16) bf16 albuf[32*264];
  __shared__ float sbuf[32*257];
  const int mt = blockIdx.x, t = blockIdx.y;
  const int b0 = mt*32;
  const int tid = threadIdx.x;
  const int wave = tid >> 6, lane = tid & 63;
  const int l16 = lane & 15, lg = lane >> 4;

  for (int i = tid; i < 1024; i += 256){
    const int r = i >> 5, cc = (i & 31) << 3;
    const int b = b0 + r;
    bf16x8 v;
    if (b < B_) v = *reinterpret_cast<const bf16x8*>(H2 + ((long)b*T_ + t)*256 + cc);
    else { 
      #pragma unroll
      for (int j=0;j<8;j++) v[j] = f2b(0.f);
    }
    *reinterpret_cast<bf16x8*>(&albuf[r*264 + cc]) = v;
  }
  __syncthreads();

  f32x4 acc[2][4];
  #pragma unroll
  for (int ms=0; ms<2; ++ms)
    #pragma unroll
    for (int ns=0; ns<4; ++ns) acc[ms][ns] = f32x4{0.f,0.f,0.f,0.f};

  const bf16* bb = Wap + (long)t*65536 + ((long)(wave*64 + l16) * 32 + lg*8);
  #pragma unroll 2
  for (int q=0; q<8; ++q){
    bf16x8 a0 = *reinterpret_cast<const bf16x8*>(&albuf[l16*264 + q*32 + lg*8]);
    bf16x8 a1 = *reinterpret_cast<const bf16x8*>(&albuf[(16 + l16)*264 + q*32 + lg*8]);
    #pragma unroll
    for (int ns=0; ns<4; ++ns){
      bf16x8 b = *reinterpret_cast<const bf16x8*>(bb + ((long)q*256 + ns*16) * 32);
      acc[0][ns] = __builtin_amdgcn_mfma_f32_16x16x32_bf16(a0, b, acc[0][ns], 0,0,0);
      acc[1][ns] = __builtin_amdgcn_mfma_f32_16x16x32_bf16(a1, b, acc[1][ns], 0,0,0);
    }
  }
  float bv[4];
  #pragma unroll
  for (int ns=0; ns<4; ++ns) bv[ns] = battn[t*256 + wave*64 + ns*16 + l16];
  #pragma unroll
  for (int ms=0; ms<2; ++ms)
    #pragma unroll
    for (int ns=0; ns<4; ++ns)
      #pragma unroll
      for (int r=0; r<4; ++r)
        sbuf[(ms*16 + lg*4 + r)*257 + wave*64 + ns*16 + l16] = acc[ms][ns][r] + bv[ns];
  __syncthreads();

  const int row = tid >> 3, seg = tid & 7;
  const float* srow = &sbuf[row*257 + seg*32];
  float v[32];
  float mx = -1e30f;
  #pragma unroll
  for (int i=0;i<32;++i){ v[i] = srow[i]; mx = fmaxf(mx, v[i]); }
  #pragma unroll
  for (int off=1; off<8; off<<=1) mx = fmaxf(mx, __shfl_xor(mx, off));
  float s = 0.f;
  #pragma unroll
  for (int i=0;i<32;++i){ v[i] = __expf(v[i] - mx); s += v[i]; }
  #pragma unroll
  for (int off=1; off<8; off<<=1) s += __shfl_xor(s, off);
  const float inv = 1.f / s;
  const int b = b0 + row;
  if (b < B_){
    const int id = ids[b*T_ + t];
    const float* ex = emb + (long)id*256 + seg*32;
    float* ap = applied + ((long)b*T_ + t)*256 + seg*32;
    bf16* fp = flat + (long)b*25856 + t*256 + seg*32;
    #pragma unroll
    for (int i=0;i<32;++i){
      const float val = v[i]*inv*ex[i];
      ap[i] = val;
      fp[i] = f2b(val);
    }
  }
}

// ---- W1 GEMM: part[ks][m][n] = flat[m][ks-slice] @ W1p, K-split 8 ----
__launch_bounds__(512)
__global__ void gemm_mlp1(const bf16* __restrict__ A, const bf16* __restrict__ Bp,
                          float* __restrict__ part)
{
  const int m0 = blockIdx.x * 32;
  const int ks = blockIdx.y;
  const int tid = threadIdx.x;
  const int wave = tid >> 6, lane = tid & 63;
  const int l16 = lane & 15, lg = lane >> 4;
  f32x4 acc[2][4];
  #pragma unroll
  for (int ms=0; ms<2; ++ms)
    #pragma unroll
    for (int ns=0; ns<4; ++ns) acc[ms][ns] = f32x4{0.f,0.f,0.f,0.f};

  const bf16* arow0 = A + (long)(m0 + l16)*25856 + lg*8;
  const bf16* arow1 = A + (long)(m0 + 16 + l16)*25856 + lg*8;
  const bf16* bb = Bp + ((long)(wave*64 + l16) * 32 + lg*8);
  #pragma unroll 2
  for (int q = ks*101; q < ks*101 + 101; ++q){
    bf16x8 a0 = *reinterpret_cast<const bf16x8*>(arow0 + (long)q*32);
    bf16x8 a1 = *reinterpret_cast<const bf16x8*>(arow1 + (long)q*32);
    #pragma unroll
    for (int ns=0; ns<4; ++ns){
      bf16x8 b = *reinterpret_cast<const bf16x8*>(bb + ((long)q*512 + ns*16) * 32);
      acc[0][ns] = __builtin_amdgcn_mfma_f32_16x16x32_bf16(a0, b, acc[0][ns], 0,0,0);
      acc[1][ns] = __builtin_amdgcn_mfma_f32_16x16x32_bf16(a1, b, acc[1][ns], 0,0,0);
    }
  }
  #pragma unroll
  for (int ms=0; ms<2; ++ms)
    #pragma unroll
    for (int ns=0; ns<4; ++ns)
      #pragma unroll
      for (int r=0; r<4; ++r)
        part[((long)ks*1024 + m0 + ms*16 + lg*4 + r)*512 + wave*64 + ns*16 + l16] = acc[ms][ns][r];
}

__global__ void reduce_relu(const float* __restrict__ part, const float* __restrict__ b1,
                            float* __restrict__ d1)
{
  const int idx = blockIdx.x*256 + threadIdx.x;   // 524288 exact
  const int n = idx & 511, m = idx >> 9;
  float s = b1[n];
  #pragma unroll
  for (int k=0;k<8;k++) s += part[((long)k*1024 + m)*512 + n];
  d1[idx] = fmaxf(s, 0.f);
}

// ---- MLP layers 2..4 fused, one block per batch row ----
__launch_bounds__(128)
__global__ void mlp_tail(const float* __restrict__ d1, const float* __restrict__ W2T,
                         const float* __restrict__ b2, const float* __restrict__ W3T,
                         const float* __restrict__ b3, const float* __restrict__ Wout,
                         const float* __restrict__ bout, float* __restrict__ tag)
{
  __shared__ float r1[512];
  __shared__ float r2[128];
  __shared__ float r3[64];
  const int b = blockIdx.x;
  const int tid = threadIdx.x;
  for (int i = tid; i < 512; i += 128) r1[i] = d1[(long)b*512 + i];
  __syncthreads();
  float a = b2[tid];
  #pragma unroll 8
  for (int k=0;k<512;++k) a += W2T[k*128 + tid] * r1[k];
  r2[tid] = fmaxf(a, 0.f);
  __syncthreads();
  if (tid < 64){
    float a3 = b3[tid];
    #pragma unroll 8
    for (int k=0;k<128;++k) a3 += W3T[k*64 + tid] * r2[k];
    r3[tid] = fmaxf(a3, 0.f);
  }
  __syncthreads();
  if (tid < 64){
    float p = r3[tid] * Wout[tid];
    #pragma unroll
    for (int off=1; off<64; off<<=1) p += __shfl_xor(p, off);
    if (tid == 0) tag[b] = p + bout[0];
  }
}

extern "C" void kernel_launch(void* const* d_in, const int* in_sizes, int n_in,
                              void* d_out, int out_size, void* d_ws, size_t ws_size,
                              hipStream_t stream)
{
  const int*   ids   = (const int*)  d_in[0];
  const float* emb   = (const float*)d_in[1];
  const float* Wih1  = (const float*)d_in[2];
  const float* Whh1  = (const float*)d_in[3];
  const float* bih1  = (const float*)d_in[4];
  const float* bhh1  = (const float*)d_in[5];
  const float* Wih2  = (const float*)d_in[6];
  const float* Whh2  = (const float*)d_in[7];
  const float* bih2  = (const float*)d_in[8];
  const float* bhh2  = (const float*)d_in[9];
  const float* Wattn = (const float*)d_in[10];
  const float* battn = (const float*)d_in[11];
  const float* W1    = (const float*)d_in[12];
  const float* b1    = (const float*)d_in[13];
  const float* W2    = (const float*)d_in[14];
  const float* b2    = (const float*)d_in[15];
  const float* W3    = (const float*)d_in[16];
  const float* b3    = (const float*)d_in[17];
  const float* Wout  = (const float*)d_in[18];
  const float* bout  = (const float*)d_in[19];
  float* out = (float*)d_out;
  char*  ws  = (char*)d_ws;

  // workspace layout (bytes)
  constexpr size_t OW_IH1 = 0;
  constexpr size_t OW_HH1 = 524288;
  constexpr size_t OW_IH2 = 1048576;
  constexpr size_t OW_HH2 = 1572864;
  constexpr size_t OW_ATT = 2097152;     // 13,238,272
  constexpr size_t OW_W1  = 15335424;    // 26,476,544
  constexpr size_t OW_W2T = 41811968;
  constexpr size_t OW_W3T = 42074112;
  constexpr size_t OB1    = 42106880;
  constexpr size_t OB2    = 42110976;
  constexpr size_t OXH2   = 42115072;    // x bf16, later h2 (alias)
  constexpr size_t OG     = 94248960;    // gates (208.5MB); later flat+part alias
  constexpr size_t OFLAT  = OG;
  constexpr size_t OPART  = OG + 52953088;
  constexpr size_t OH1    = 302784512;
  constexpr size_t OD1    = 354918400;
  constexpr size_t NEED   = 357015552;
  if (ws_size < NEED) return;

  bf16*  pIH1 = (bf16*) (ws + OW_IH1);
  bf16*  pHH1 = (bf16*) (ws + OW_HH1);
  bf16*  pIH2 = (bf16*) (ws + OW_IH2);
  bf16*  pHH2 = (bf16*) (ws + OW_HH2);
  bf16*  pATT = (bf16*) (ws + OW_ATT);
  bf16*  pW1  = (bf16*) (ws + OW_W1);
  float* pW2T = (float*)(ws + OW_W2T);
  float* pW3T = (float*)(ws + OW_W3T);
  float* pB1  = (float*)(ws + OB1);
  float* pB2  = (float*)(ws + OB2);
  bf16*  pXH2 = (bf16*) (ws + OXH2);
  bf16*  pG   = (bf16*) (ws + OG);
  bf16*  pFLAT= (bf16*) (ws + OFLAT);
  float* pPART= (float*)(ws + OPART);
  bf16*  pH1  = (bf16*) (ws + OH1);
  float* pD1  = (float*)(ws + OD1);

  // zero h1 pad tail (rows 101808..101823) before g2 GEMM reads it
  hipMemsetAsync(ws + OH1 + (size_t)101808*512, 0, (size_t)16*512, stream);

  // weight packing
  pack_bT<<<dim3(128),        256, 0, stream>>>(Wih1,  pIH1, 1024, 256);
  pack_bT<<<dim3(128),        256, 0, stream>>>(Whh1,  pHH1, 1024, 256);
  pack_bT<<<dim3(128),        256, 0, stream>>>(Wih2,  pIH2, 1024, 256);
  pack_bT<<<dim3(128),        256, 0, stream>>>(Whh2,  pHH2, 1024, 256);
  pack_bT<<<dim3(32, 101),    256, 0, stream>>>(Wattn, pATT, 256,  256);
  pack_bT<<<dim3(6464),       256, 0, stream>>>(W1,    pW1,  512,  25856);
  tr_f32 <<<dim3(256),        256, 0, stream>>>(W2, pW2T, 128, 512);
  tr_f32 <<<dim3(32),         256, 0, stream>>>(W3, pW3T, 64, 128);
  bias_sum<<<dim3(4),         256, 0, stream>>>(bih1, bhh1, pB1, 1024);
  bias_sum<<<dim3(4),         256, 0, stream>>>(bih2, bhh2, pB2, 1024);

  // embed -> x bf16
  embed_k<<<dim3(12728), 256, 0, stream>>>(ids, emb, pXH2);

  // layer 1
  gemm_gates <<<dim3(1591), 512, 0, stream>>>(pXH2, pIH1, pB1, pG);
  lstm_hybrid<<<dim3(63),   512, 0, stream>>>(pG, pHH1, pH1);
  // layer 2
  gemm_gates <<<dim3(1591), 512, 0, stream>>>(pH1, pIH2, pB2, pG);
  lstm_hybrid<<<dim3(63),   512, 0, stream>>>(pG, pHH2, pXH2);   // h2 -> XH2 alias

  // flat pad rows [1000,1024) zero (after gates buffer is dead)
  hipMemsetAsync(ws + OFLAT + (size_t)B_*25856*2, 0, (size_t)24*25856*2, stream);

  // attention + softmax + applied (writes d_out applied region + flat bf16)
  attn_applied<<<dim3(32, 101), 256, 0, stream>>>(pXH2, pATT, battn, ids, emb,
                                                  out + 1000, pFLAT);

  // MLP
  gemm_mlp1  <<<dim3(32, 8), 512, 0, stream>>>(pFLAT, pW1, pPART);
  reduce_relu<<<dim3(2048),  256, 0, stream>>>(pPART, b1, pD1);
  mlp_tail   <<<dim3(1000),  128, 0, stream>>>(pD1, pW2T, b2, pW3T, b3, Wout, bout, out);
}

// Round 7
// 1223.935 us; speedup vs baseline: 3.5046x; 1.7955x over previous
//
#include <hip/hip_runtime.h>
#include <hip/hip_bf16.h>

// AttnDecoderRNN on MI355X.
// R2: streaming LSTM 63 WGs x 16 rows (798 us/layer).
// R3: 4-WG split + acquire/release exchange — FAILED: fences caused L2
//     wb/inv every step, FETCH doubled, G re-fetched from HBM.
// R4/R5: register-resident Whh — FAILED: allocator spills long-lived
//     VGPR arrays across barrier loops (VGPR_Count 108/128 proved it).
// R6: 4-way col-split, 252 WGs; per-WG stream drops to 128KB/step
//     (proven R2 dual-buffer); h exchanged via PURE-LLC relaxed
//     agent-scope atomics (sc1, no cache maintenance), ordered by
//     __syncthreads vmcnt drain + relaxed flag counter + bounded poll.

#define B_    1000
#define T_    101
#define E_    256
#define H_    256
#define BPAD  1008      // 63 * 16
#define MPAD  101824    // 1591 * 64  >= BPAD*T_ = 101808
#define NG    1024      // 4H
#define NSLICE 63

typedef __bf16 bf16;
typedef __bf16 bf16x8 __attribute__((ext_vector_type(8)));
typedef float  f32x4  __attribute__((ext_vector_type(4)));

__device__ __forceinline__ bf16 f2b(float f){
  unsigned u = __builtin_bit_cast(unsigned, f);
  u += 0x7FFFu + ((u >> 16) & 1u);               // RNE
  unsigned short h = (unsigned short)(u >> 16);
  return __builtin_bit_cast(bf16, h);
}
__device__ __forceinline__ float b2f(bf16 v){
  unsigned short s = __builtin_bit_cast(unsigned short, v);
  unsigned u = ((unsigned)s) << 16;
  return __builtin_bit_cast(float, u);
}
__device__ __forceinline__ float bflo(unsigned u){ return __builtin_bit_cast(float, u << 16); }
__device__ __forceinline__ float bfhi(unsigned u){ return __builtin_bit_cast(float, u & 0xffff0000u); }
__device__ __forceinline__ unsigned packbf(float a, float b){
  unsigned ua = __builtin_bit_cast(unsigned, a);
  ua += 0x7FFFu + ((ua >> 16) & 1u);
  unsigned ub = __builtin_bit_cast(unsigned, b);
  ub += 0x7FFFu + ((ub >> 16) & 1u);
  return (ua >> 16) | (ub & 0xffff0000u);
}
__device__ __forceinline__ float sigm(float x){ return 1.f/(1.f + __expf(-x)); }
__device__ __forceinline__ float tanh_(float x){ return 2.f/(1.f + __expf(-2.f*x)) - 1.f; }

// ---- pack W[N][K] f32 -> Bp[K/32][N][32] bf16 (MFMA B-fragment order) ----
__global__ void pack_bT(const float* __restrict__ src, bf16* __restrict__ dst,
                        int N, int K)
{
  const long batch = blockIdx.y;
  src += batch * (long)N * K;
  dst += batch * (long)(K/32) * N * 32;
  const int tid = blockIdx.x * blockDim.x + threadIdx.x;
  const int total = (K/32) * N * 4;
  if (tid >= total) return;
  const int kkc = tid & 3;
  const int rem = tid >> 2;
  const int n = rem % N;
  const int q = rem / N;
  const float* s = src + (long)n*K + q*32 + kkc*8;
  bf16x8 v;
  #pragma unroll
  for (int e=0;e<8;e++) v[e] = f2b(s[e]);
  *reinterpret_cast<bf16x8*>(dst + ((long)q*N + n)*32 + kkc*8) = v;
}

// ---- f32 transpose: dst[k][j] = src[j][k], src is [N][K] ----
__global__ void tr_f32(const float* __restrict__ src, float* __restrict__ dst,
                       int N, int K)
{
  const int id = blockIdx.x * blockDim.x + threadIdx.x;
  if (id >= N*K) return;
  const int k = id / N, j = id % N;
  dst[(long)k*N + j] = src[(long)j*K + k];
}

__global__ void bias_sum(const float* __restrict__ a, const float* __restrict__ b,
                         float* __restrict__ o, int n)
{
  const int i = blockIdx.x * blockDim.x + threadIdx.x;
  if (i < n) o[i] = a[i] + b[i];
}

// ---- embedding gather -> x bf16 [MPAD][256], zeros for pad rows ----
__global__ void embed_k(const int* __restrict__ ids, const float* __restrict__ emb,
                        bf16* __restrict__ x)
{
  const int tid = blockIdx.x * blockDim.x + threadIdx.x;   // MPAD*32 exact
  const int m = tid >> 5;
  const int c = (tid & 31) << 3;
  bf16x8 v;
  if (m < B_*T_) {
    const int id = ids[m];
    const float* e = emb + (long)id*E_ + c;
    #pragma unroll
    for (int j=0;j<8;j++) v[j] = f2b(e[j]);
  } else {
    #pragma unroll
    for (int j=0;j<8;j++) v[j] = f2b(0.f);
  }
  *reinterpret_cast<bf16x8*>(x + (long)m*256 + c) = v;
}

// ---- gates GEMM: G[m][1024] = A[m][256] @ Bp + bias, bf16 out ----
__launch_bounds__(512)
__global__ void gemm_gates(const bf16* __restrict__ A, const bf16* __restrict__ Bp,
                           const float* __restrict__ bias, bf16* __restrict__ Gout)
{
  __shared__ __align__(16) bf16 smem[17408];   // A: 64x264 ; epilogue stage: 8 x 16x136
  const int m0 = blockIdx.x * 64;
  const int tid = threadIdx.x;
  const int wave = tid >> 6;
  const int lane = tid & 63;
  const int l16 = lane & 15, lg = lane >> 4;

  for (int i = tid; i < 2048; i += 512){
    const int r = i >> 5, cc = (i & 31) << 3;
    *reinterpret_cast<bf16x8*>(&smem[r*264 + cc]) =
      *reinterpret_cast<const bf16x8*>(A + (long)(m0 + r)*256 + cc);
  }
  __syncthreads();

  f32x4 acc[4][8];
  #pragma unroll
  for (int ms=0; ms<4; ++ms)
    #pragma unroll
    for (int ns=0; ns<8; ++ns) acc[ms][ns] = f32x4{0.f,0.f,0.f,0.f};

  const bf16* bb = Bp + ((long)(wave*128 + l16) * 32 + lg*8);
  #pragma unroll 2
  for (int q=0; q<8; ++q){
    bf16x8 af[4];
    #pragma unroll
    for (int ms=0; ms<4; ++ms)
      af[ms] = *reinterpret_cast<const bf16x8*>(&smem[(ms*16 + l16)*264 + q*32 + lg*8]);
    bf16x8 bfr[8];
    #pragma unroll
    for (int ns=0; ns<8; ++ns)
      bfr[ns] = *reinterpret_cast<const bf16x8*>(bb + ((long)q*NG + ns*16) * 32);
    #pragma unroll
    for (int ms=0; ms<4; ++ms)
      #pragma unroll
      for (int ns=0; ns<8; ++ns)
        acc[ms][ns] = __builtin_amdgcn_mfma_f32_16x16x32_bf16(af[ms], bfr[ns], acc[ms][ns], 0,0,0);
  }

  float bv[8];
  #pragma unroll
  for (int ns=0; ns<8; ++ns) bv[ns] = bias[wave*128 + ns*16 + l16];

  bf16* stage = smem + wave*2176;
  #pragma unroll
  for (int ms=0; ms<4; ++ms){
    __syncthreads();
    #pragma unroll
    for (int ns=0; ns<8; ++ns)
      #pragma unroll
      for (int r=0; r<4; ++r)
        stage[(lg*4 + r)*136 + ns*16 + l16] = f2b(acc[ms][ns][r] + bv[ns]);
    __syncthreads();
    const int row = lane >> 2, ch = lane & 3;
    bf16* gout = Gout + (long)(m0 + ms*16 + row)*NG + wave*128;
    #pragma unroll
    for (int cc2=0; cc2<4; ++cc2){
      const int chunk = ch + cc2*4;
      *reinterpret_cast<bf16x8*>(gout + chunk*8) =
        *reinterpret_cast<const bf16x8*>(&stage[row*136 + chunk*8]);
    }
  }
}

// ---- R6 persistent LSTM: 63 slices x 4 WGs (col-split), LLC exchange ----
// WG (s,g): rows [16s,16s+16), h-cols [g*64,(g+1)*64), gate cols
// {qd*256 + g*64 + [0,64) : qd=0..3}. Wave w handles local gate cols
// jl = w*32 + ns*16 + l16 (jl = gate*64 + within-64 index).
__launch_bounds__(512)
__global__ void lstm_x4(const bf16* __restrict__ G, const bf16* __restrict__ Bp,
                        bf16* __restrict__ Hout, unsigned* __restrict__ hX,
                        unsigned* __restrict__ flags)
{
  __shared__ __align__(16) bf16 hbuf[16*264];   // full h (16 x 256), padded
  __shared__ float gstage[256*17];               // gate partials [local col][row]
  const int bid = blockIdx.x;
  const int s = bid >> 2, g = bid & 3;
  const int b0 = s * 16;
  const int tid = threadIdx.x;
  const int wave = tid >> 6, lane = tid & 63;
  const int l16 = lane & 15, lg = lane >> 4;
  const int qd  = wave >> 1;               // gate quadrant of this wave
  const int h32 = (wave & 1) * 32;         // 32-col half within the 64

  // B-frag stream base: gcol(ns) = qd*256 + g*64 + h32 + ns*16 + l16
  const bf16* bb = Bp + ((long)(qd*256 + g*64 + h32 + l16) * 32 + lg*8);

  for (int i = tid; i < 16*264; i += 512) hbuf[i] = f2b(0.f);

  // elementwise / publish mapping: thread -> (row, h-cols j2, j2+1)
  const int row = tid >> 5;            // 0..15
  const int k32 = tid & 31;
  const int j2  = k32 * 2;             // [0,64)
  float c0 = 0.f, c1 = 0.f;

  const long grow = (long)(b0 + row) * T_;
  const bf16* gptr = G + grow*NG + g*64 + j2;      // +{0,256,512,768}
  bf16*       hop  = Hout + grow*256 + g*64 + j2;

  unsigned* flag = flags + s*16;                    // 64B-padded per slice
  unsigned* hx0 = hX + (size_t)s*2048 + row*128 + g*32 + k32;
  unsigned* hx1 = hx0 + (size_t)NSLICE*2048;
  const unsigned* rb0 = hX + (size_t)s*2048 + row*128;
  const unsigned* rb1 = rb0 + (size_t)NSLICE*2048;

  __syncthreads();

  for (int t = 0; t < T_; ++t){
    // --- G prefetch (independent; consumed after B1) ---
    const bf16* gp = gptr + (long)t*NG;
    const unsigned vI = *reinterpret_cast<const unsigned*>(gp);
    const unsigned vF = *reinterpret_cast<const unsigned*>(gp + 256);
    const unsigned vG = *reinterpret_cast<const unsigned*>(gp + 512);
    const unsigned vO = *reinterpret_cast<const unsigned*>(gp + 768);

    // --- MFMA: 2 col-frags, K=256, dual-buffered 128KB/WG stream ---
    f32x4 acc0 = {0.f,0.f,0.f,0.f}, acc1 = {0.f,0.f,0.f,0.f};
    bf16x8 sA0, sA1, sB0, sB1;
    sA0 = *reinterpret_cast<const bf16x8*>(bb + (0L*NG +  0)*32);
    sA1 = *reinterpret_cast<const bf16x8*>(bb + (0L*NG + 16)*32);
    #pragma unroll
    for (int h2=0; h2<4; ++h2){
      const int q0 = 2*h2;
      sB0 = *reinterpret_cast<const bf16x8*>(bb + ((long)(q0+1)*NG +  0)*32);
      sB1 = *reinterpret_cast<const bf16x8*>(bb + ((long)(q0+1)*NG + 16)*32);
      {
        bf16x8 a = *reinterpret_cast<const bf16x8*>(&hbuf[l16*264 + q0*32 + lg*8]);
        acc0 = __builtin_amdgcn_mfma_f32_16x16x32_bf16(a, sA0, acc0, 0,0,0);
        acc1 = __builtin_amdgcn_mfma_f32_16x16x32_bf16(a, sA1, acc1, 0,0,0);
      }
      if (q0+2 < 8){
        sA0 = *reinterpret_cast<const bf16x8*>(bb + ((long)(q0+2)*NG +  0)*32);
        sA1 = *reinterpret_cast<const bf16x8*>(bb + ((long)(q0+2)*NG + 16)*32);
      }
      {
        bf16x8 a = *reinterpret_cast<const bf16x8*>(&hbuf[l16*264 + (q0+1)*32 + lg*8]);
        acc0 = __builtin_amdgcn_mfma_f32_16x16x32_bf16(a, sB0, acc0, 0,0,0);
        acc1 = __builtin_amdgcn_mfma_f32_16x16x32_bf16(a, sB1, acc1, 0,0,0);
      }
    }
    // dump gate partials, transposed [local col][17]
    {
      const int jj = wave*32 + l16;
      float* gc0 = &gstage[jj*17 + lg*4];
      gc0[0]=acc0[0]; gc0[1]=acc0[1]; gc0[2]=acc0[2]; gc0[3]=acc0[3];
      float* gc1 = &gstage[(jj+16)*17 + lg*4];
      gc1[0]=acc1[0]; gc1[1]=acc1[1]; gc1[2]=acc1[2]; gc1[3]=acc1[3];
    }
    __syncthreads();   // B1: gstage visible; hbuf reads done

    // --- elementwise: 2 h-cols per thread ---
    const float i0 = sigm (bflo(vI) + gstage[(j2      )*17 + row]);
    const float i1 = sigm (bfhi(vI) + gstage[(j2 +   1)*17 + row]);
    const float f0 = sigm (bflo(vF) + gstage[(j2 +  64)*17 + row]);
    const float f1 = sigm (bfhi(vF) + gstage[(j2 +  65)*17 + row]);
    const float g0 = tanh_(bflo(vG) + gstage[(j2 + 128)*17 + row]);
    const float g1 = tanh_(bfhi(vG) + gstage[(j2 + 129)*17 + row]);
    const float o0 = sigm (bflo(vO) + gstage[(j2 + 192)*17 + row]);
    const float o1 = sigm (bfhi(vO) + gstage[(j2 + 193)*17 + row]);
    c0 = f0*c0 + i0*g0;
    c1 = f1*c1 + i1*g1;
    const unsigned hw = packbf(o0*tanh_(c0), o1*tanh_(c1));

    // own block -> hbuf; publish -> LLC (relaxed sc1, no fences); Hout plain
    *reinterpret_cast<unsigned*>(&hbuf[row*264 + g*64 + j2]) = hw;
    __hip_atomic_store((t&1) ? hx1 : hx0, hw, __ATOMIC_RELAXED, __HIP_MEMORY_SCOPE_AGENT);
    *reinterpret_cast<unsigned*>(hop + (long)t*256) = hw;

    __syncthreads();   // B2: vmcnt(0) drain on every wave, then barrier
    if (tid == 0)
      __hip_atomic_fetch_add(flag, 1u, __ATOMIC_RELAXED, __HIP_MEMORY_SCOPE_AGENT);

    // --- wait all 4 WGs of this slice, then pull siblings' h-blocks ---
    {
      const unsigned tgt = 4u*(t+1);
      if (lane == 0){
        int guard = 0;
        while (__hip_atomic_load(flag, __ATOMIC_RELAXED, __HIP_MEMORY_SCOPE_AGENT) < tgt
               && ++guard < (1<<20))
          __builtin_amdgcn_s_sleep(1);
      }
      asm volatile("" ::: "memory");
      __builtin_amdgcn_sched_barrier(0);
      const unsigned* rb = (t&1) ? rb1 : rb0;
      #pragma unroll
      for (int sb=1; sb<4; ++sb){
        const int g2 = (g + sb) & 3;
        const unsigned w = __hip_atomic_load(rb + g2*32 + k32,
                                             __ATOMIC_RELAXED, __HIP_MEMORY_SCOPE_AGENT);
        *reinterpret_cast<unsigned*>(&hbuf[row*264 + g2*64 + j2]) = w;
      }
    }
    __syncthreads();   // B3: hbuf complete for next step
  }
}

// ---- fused attention GEMM + softmax + applied (w*x) + flat bf16 ----
__launch_bounds__(256)
__global__ void attn_applied(const bf16* __restrict__ H2, const bf16* __restrict__ Wap,
                             const float* __restrict__ battn, const int* __restrict__ ids,
                             const float* __restrict__ emb, float* __restrict__ applied,
                             bf16* __restrict__ flat)
{
  __shared__ __align__(16) bf16 albuf[32*264];
  __shared__ float sbuf[32*257];
  const int mt = blockIdx.x, t = blockIdx.y;
  const int b0 = mt*32;
  const int tid = threadIdx.x;
  const int wave = tid >> 6, lane = tid & 63;
  const int l16 = lane & 15, lg = lane >> 4;

  for (int i = tid; i < 1024; i += 256){
    const int r = i >> 5, cc = (i & 31) << 3;
    const int b = b0 + r;
    bf16x8 v;
    if (b < B_) v = *reinterpret_cast<const bf16x8*>(H2 + ((long)b*T_ + t)*256 + cc);
    else { 
      #pragma unroll
      for (int j=0;j<8;j++) v[j] = f2b(0.f);
    }
    *reinterpret_cast<bf16x8*>(&albuf[r*264 + cc]) = v;
  }
  __syncthreads();

  f32x4 acc[2][4];
  #pragma unroll
  for (int ms=0; ms<2; ++ms)
    #pragma unroll
    for (int ns=0; ns<4; ++ns) acc[ms][ns] = f32x4{0.f,0.f,0.f,0.f};

  const bf16* bb = Wap + (long)t*65536 + ((long)(wave*64 + l16) * 32 + lg*8);
  #pragma unroll 2
  for (int q=0; q<8; ++q){
    bf16x8 a0 = *reinterpret_cast<const bf16x8*>(&albuf[l16*264 + q*32 + lg*8]);
    bf16x8 a1 = *reinterpret_cast<const bf16x8*>(&albuf[(16 + l16)*264 + q*32 + lg*8]);
    #pragma unroll
    for (int ns=0; ns<4; ++ns){
      bf16x8 b = *reinterpret_cast<const bf16x8*>(bb + ((long)q*256 + ns*16) * 32);
      acc[0][ns] = __builtin_amdgcn_mfma_f32_16x16x32_bf16(a0, b, acc[0][ns], 0,0,0);
      acc[1][ns] = __builtin_amdgcn_mfma_f32_16x16x32_bf16(a1, b, acc[1][ns], 0,0,0);
    }
  }
  float bv[4];
  #pragma unroll
  for (int ns=0; ns<4; ++ns) bv[ns] = battn[t*256 + wave*64 + ns*16 + l16];
  #pragma unroll
  for (int ms=0; ms<2; ++ms)
    #pragma unroll
    for (int ns=0; ns<4; ++ns)
      #pragma unroll
      for (int r=0; r<4; ++r)
        sbuf[(ms*16 + lg*4 + r)*257 + wave*64 + ns*16 + l16] = acc[ms][ns][r] + bv[ns];
  __syncthreads();

  const int row = tid >> 3, seg = tid & 7;
  const float* srow = &sbuf[row*257 + seg*32];
  float v[32];
  float mx = -1e30f;
  #pragma unroll
  for (int i=0;i<32;++i){ v[i] = srow[i]; mx = fmaxf(mx, v[i]); }
  #pragma unroll
  for (int off=1; off<8; off<<=1) mx = fmaxf(mx, __shfl_xor(mx, off));
  float s = 0.f;
  #pragma unroll
  for (int i=0;i<32;++i){ v[i] = __expf(v[i] - mx); s += v[i]; }
  #pragma unroll
  for (int off=1; off<8; off<<=1) s += __shfl_xor(s, off);
  const float inv = 1.f / s;
  const int b = b0 + row;
  if (b < B_){
    const int id = ids[b*T_ + t];
    const float* ex = emb + (long)id*256 + seg*32;
    float* ap = applied + ((long)b*T_ + t)*256 + seg*32;
    bf16* fp = flat + (long)b*25856 + t*256 + seg*32;
    #pragma unroll
    for (int i=0;i<32;++i){
      const float val = v[i]*inv*ex[i];
      ap[i] = val;
      fp[i] = f2b(val);
    }
  }
}

// ---- W1 GEMM: part[ks][m][n] = flat[m][ks-slice] @ W1p, K-split 8 ----
__launch_bounds__(512)
__global__ void gemm_mlp1(const bf16* __restrict__ A, const bf16* __restrict__ Bp,
                          float* __restrict__ part)
{
  const int m0 = blockIdx.x * 32;
  const int ks = blockIdx.y;
  const int tid = threadIdx.x;
  const int wave = tid >> 6, lane = tid & 63;
  const int l16 = lane & 15, lg = lane >> 4;
  f32x4 acc[2][4];
  #pragma unroll
  for (int ms=0; ms<2; ++ms)
    #pragma unroll
    for (int ns=0; ns<4; ++ns) acc[ms][ns] = f32x4{0.f,0.f,0.f,0.f};

  const bf16* arow0 = A + (long)(m0 + l16)*25856 + lg*8;
  const bf16* arow1 = A + (long)(m0 + 16 + l16)*25856 + lg*8;
  const bf16* bb = Bp + ((long)(wave*64 + l16) * 32 + lg*8);
  #pragma unroll 2
  for (int q = ks*101; q < ks*101 + 101; ++q){
    bf16x8 a0 = *reinterpret_cast<const bf16x8*>(arow0 + (long)q*32);
    bf16x8 a1 = *reinterpret_cast<const bf16x8*>(arow1 + (long)q*32);
    #pragma unroll
    for (int ns=0; ns<4; ++ns){
      bf16x8 b = *reinterpret_cast<const bf16x8*>(bb + ((long)q*512 + ns*16) * 32);
      acc[0][ns] = __builtin_amdgcn_mfma_f32_16x16x32_bf16(a0, b, acc[0][ns], 0,0,0);
      acc[1][ns] = __builtin_amdgcn_mfma_f32_16x16x32_bf16(a1, b, acc[1][ns], 0,0,0);
    }
  }
  #pragma unroll
  for (int ms=0; ms<2; ++ms)
    #pragma unroll
    for (int ns=0; ns<4; ++ns)
      #pragma unroll
      for (int r=0; r<4; ++r)
        part[((long)ks*1024 + m0 + ms*16 + lg*4 + r)*512 + wave*64 + ns*16 + l16] = acc[ms][ns][r];
}

__global__ void reduce_relu(const float* __restrict__ part, const float* __restrict__ b1,
                            float* __restrict__ d1)
{
  const int idx = blockIdx.x*256 + threadIdx.x;   // 524288 exact
  const int n = idx & 511, m = idx >> 9;
  float s = b1[n];
  #pragma unroll
  for (int k=0;k<8;k++) s += part[((long)k*1024 + m)*512 + n];
  d1[idx] = fmaxf(s, 0.f);
}

// ---- MLP layers 2..4 fused, one block per batch row ----
__launch_bounds__(128)
__global__ void mlp_tail(const float* __restrict__ d1, const float* __restrict__ W2T,
                         const float* __restrict__ b2, const float* __restrict__ W3T,
                         const float* __restrict__ b3, const float* __restrict__ Wout,
                         const float* __restrict__ bout, float* __restrict__ tag)
{
  __shared__ float r1[512];
  __shared__ float r2[128];
  __shared__ float r3[64];
  const int b = blockIdx.x;
  const int tid = threadIdx.x;
  for (int i = tid; i < 512; i += 128) r1[i] = d1[(long)b*512 + i];
  __syncthreads();
  float a = b2[tid];
  #pragma unroll 8
  for (int k=0;k<512;++k) a += W2T[k*128 + tid] * r1[k];
  r2[tid] = fmaxf(a, 0.f);
  __syncthreads();
  if (tid < 64){
    float a3 = b3[tid];
    #pragma unroll 8
    for (int k=0;k<128;++k) a3 += W3T[k*64 + tid] * r2[k];
    r3[tid] = fmaxf(a3, 0.f);
  }
  __syncthreads();
  if (tid < 64){
    float p = r3[tid] * Wout[tid];
    #pragma unroll
    for (int off=1; off<64; off<<=1) p += __shfl_xor(p, off);
    if (tid == 0) tag[b] = p + bout[0];
  }
}

extern "C" void kernel_launch(void* const* d_in, const int* in_sizes, int n_in,
                              void* d_out, int out_size, void* d_ws, size_t ws_size,
                              hipStream_t stream)
{
  const int*   ids   = (const int*)  d_in[0];
  const float* emb   = (const float*)d_in[1];
  const float* Wih1  = (const float*)d_in[2];
  const float* Whh1  = (const float*)d_in[3];
  const float* bih1  = (const float*)d_in[4];
  const float* bhh1  = (const float*)d_in[5];
  const float* Wih2  = (const float*)d_in[6];
  const float* Whh2  = (const float*)d_in[7];
  const float* bih2  = (const float*)d_in[8];
  const float* bhh2  = (const float*)d_in[9];
  const float* Wattn = (const float*)d_in[10];
  const float* battn = (const float*)d_in[11];
  const float* W1    = (const float*)d_in[12];
  const float* b1    = (const float*)d_in[13];
  const float* W2    = (const float*)d_in[14];
  const float* b2    = (const float*)d_in[15];
  const float* W3    = (const float*)d_in[16];
  const float* b3    = (const float*)d_in[17];
  const float* Wout  = (const float*)d_in[18];
  const float* bout  = (const float*)d_in[19];
  float* out = (float*)d_out;
  char*  ws  = (char*)d_ws;

  // workspace layout (bytes)
  constexpr size_t OW_IH1 = 0;
  constexpr size_t OW_HH1 = 524288;
  constexpr size_t OW_IH2 = 1048576;
  constexpr size_t OW_HH2 = 1572864;
  constexpr size_t OW_ATT = 2097152;     // 13,238,272
  constexpr size_t OW_W1  = 15335424;    // 26,476,544
  constexpr size_t OW_W2T = 41811968;
  constexpr size_t OW_W3T = 42074112;
  constexpr size_t OB1    = 42106880;
  constexpr size_t OB2    = 42110976;
  constexpr size_t OXH2   = 42115072;    // x bf16, later h2 (alias)
  constexpr size_t OG     = 94248960;    // gates (208.5MB); later flat+part alias
  constexpr size_t OFLAT  = OG;
  constexpr size_t OPART  = OG + 52953088;
  constexpr size_t OH1    = 302784512;
  constexpr size_t OD1    = 354918400;   // d1 (2MB) — dead during LSTMs:
  constexpr size_t OHX    = OD1;         //   hX: 2 parity x 63 x 8KB = 1,032,192
  constexpr size_t OFLG   = OD1 + 1032192; // flags: 2 layers x 4KB
  constexpr size_t NEED   = 357015552;
  if (ws_size < NEED) return;

  bf16*  pIH1 = (bf16*) (ws + OW_IH1);
  bf16*  pHH1 = (bf16*) (ws + OW_HH1);
  bf16*  pIH2 = (bf16*) (ws + OW_IH2);
  bf16*  pHH2 = (bf16*) (ws + OW_HH2);
  bf16*  pATT = (bf16*) (ws + OW_ATT);
  bf16*  pW1  = (bf16*) (ws + OW_W1);
  float* pW2T = (float*)(ws + OW_W2T);
  float* pW3T = (float*)(ws + OW_W3T);
  float* pB1  = (float*)(ws + OB1);
  float* pB2  = (float*)(ws + OB2);
  bf16*  pXH2 = (bf16*) (ws + OXH2);
  bf16*  pG   = (bf16*) (ws + OG);
  bf16*  pFLAT= (bf16*) (ws + OFLAT);
  float* pPART= (float*)(ws + OPART);
  bf16*  pH1  = (bf16*) (ws + OH1);
  float* pD1  = (float*)(ws + OD1);
  unsigned* pHX  = (unsigned*)(ws + OHX);
  unsigned* pFL1 = (unsigned*)(ws + OFLG);
  unsigned* pFL2 = (unsigned*)(ws + OFLG + 4096);

  // zero h1 pad tail (rows 101808..101823) before g2 GEMM reads it
  hipMemsetAsync(ws + OH1 + (size_t)101808*512, 0, (size_t)16*512, stream);
  // zero exchange flags for both LSTM layers (graph-replay safe)
  hipMemsetAsync(ws + OFLG, 0, 8192, stream);

  // weight packing
  pack_bT<<<dim3(128),        256, 0, stream>>>(Wih1,  pIH1, 1024, 256);
  pack_bT<<<dim3(128),        256, 0, stream>>>(Whh1,  pHH1, 1024, 256);
  pack_bT<<<dim3(128),        256, 0, stream>>>(Wih2,  pIH2, 1024, 256);
  pack_bT<<<dim3(128),        256, 0, stream>>>(Whh2,  pHH2, 1024, 256);
  pack_bT<<<dim3(32, 101),    256, 0, stream>>>(Wattn, pATT, 256,  256);
  pack_bT<<<dim3(6464),       256, 0, stream>>>(W1,    pW1,  512,  25856);
  tr_f32 <<<dim3(256),        256, 0, stream>>>(W2, pW2T, 128, 512);
  tr_f32 <<<dim3(32),         256, 0, stream>>>(W3, pW3T, 64, 128);
  bias_sum<<<dim3(4),         256, 0, stream>>>(bih1, bhh1, pB1, 1024);
  bias_sum<<<dim3(4),         256, 0, stream>>>(bih2, bhh2, pB2, 1024);

  // embed -> x bf16
  embed_k<<<dim3(12728), 256, 0, stream>>>(ids, emb, pXH2);

  // layer 1
  gemm_gates<<<dim3(1591), 512, 0, stream>>>(pXH2, pIH1, pB1, pG);
  lstm_x4   <<<dim3(252),  512, 0, stream>>>(pG, pHH1, pH1, pHX, pFL1);
  // layer 2
  gemm_gates<<<dim3(1591), 512, 0, stream>>>(pH1, pIH2, pB2, pG);
  lstm_x4   <<<dim3(252),  512, 0, stream>>>(pG, pHH2, pXH2, pHX, pFL2);

  // flat pad rows [1000,1024) zero (after gates buffer is dead)
  hipMemsetAsync(ws + OFLAT + (size_t)B_*25856*2, 0, (size_t)24*25856*2, stream);

  // attention + softmax + applied (writes d_out applied region + flat bf16)
  attn_applied<<<dim3(32, 101), 256, 0, stream>>>(pXH2, pATT, battn, ids, emb,
                                                  out + 1000, pFLAT);

  // MLP
  gemm_mlp1  <<<dim3(32, 8), 512, 0, stream>>>(pFLAT, pW1, pPART);
  reduce_relu<<<dim3(2048),  256, 0, stream>>>(pPART, b1, pD1);
  mlp_tail   <<<dim3(1000),  128, 0, stream>>>(pD1, pW2T, b2, pW3T, b3, Wout, bout, out);
}

// Round 8
// 1139.372 us; speedup vs baseline: 3.7648x; 1.0742x over previous
//
#include <hip/hip_runtime.h>
#include <hip/hip_bf16.h>

// AttnDecoderRNN on MI355X.
// R2: streaming LSTM 63 WGs x 16 rows (798 us/layer).
// R3-R5: register-resident Whh attempts — FAILED (allocator spills /
//        acquire-release cache maintenance poisons L2).
// R6: 4-way col-split, 252 WGs, 128KB/step stream + pure-LLC relaxed
//     exchange (348 us/layer). WIN.
// R7: (a) lstm_x4 — own-K MFMA + next-iter B-frag prefetch moved into
//     the exchange-wait window (acc carried across iterations); remK
//     (6 chunks) completes gates at top of next iter. (b) gemm_gates —
//     launch_bounds(512,2) + explicit dual-buffered B pipeline (R2 fix).

#define B_    1000
#define T_    101
#define E_    256
#define H_    256
#define BPAD  1008      // 63 * 16
#define MPAD  101824    // 1591 * 64  >= BPAD*T_ = 101808
#define NG    1024      // 4H
#define NSLICE 63

typedef __bf16 bf16;
typedef __bf16 bf16x8 __attribute__((ext_vector_type(8)));
typedef float  f32x4  __attribute__((ext_vector_type(4)));

__device__ __forceinline__ bf16 f2b(float f){
  unsigned u = __builtin_bit_cast(unsigned, f);
  u += 0x7FFFu + ((u >> 16) & 1u);               // RNE
  unsigned short h = (unsigned short)(u >> 16);
  return __builtin_bit_cast(bf16, h);
}
__device__ __forceinline__ float b2f(bf16 v){
  unsigned short s = __builtin_bit_cast(unsigned short, v);
  unsigned u = ((unsigned)s) << 16;
  return __builtin_bit_cast(float, u);
}
__device__ __forceinline__ float bflo(unsigned u){ return __builtin_bit_cast(float, u << 16); }
__device__ __forceinline__ float bfhi(unsigned u){ return __builtin_bit_cast(float, u & 0xffff0000u); }
__device__ __forceinline__ unsigned packbf(float a, float b){
  unsigned ua = __builtin_bit_cast(unsigned, a);
  ua += 0x7FFFu + ((ua >> 16) & 1u);
  unsigned ub = __builtin_bit_cast(unsigned, b);
  ub += 0x7FFFu + ((ub >> 16) & 1u);
  return (ua >> 16) | (ub & 0xffff0000u);
}
__device__ __forceinline__ float sigm(float x){ return 1.f/(1.f + __expf(-x)); }
__device__ __forceinline__ float tanh_(float x){ return 2.f/(1.f + __expf(-2.f*x)) - 1.f; }

// ---- pack W[N][K] f32 -> Bp[K/32][N][32] bf16 (MFMA B-fragment order) ----
__global__ void pack_bT(const float* __restrict__ src, bf16* __restrict__ dst,
                        int N, int K)
{
  const long batch = blockIdx.y;
  src += batch * (long)N * K;
  dst += batch * (long)(K/32) * N * 32;
  const int tid = blockIdx.x * blockDim.x + threadIdx.x;
  const int total = (K/32) * N * 4;
  if (tid >= total) return;
  const int kkc = tid & 3;
  const int rem = tid >> 2;
  const int n = rem % N;
  const int q = rem / N;
  const float* s = src + (long)n*K + q*32 + kkc*8;
  bf16x8 v;
  #pragma unroll
  for (int e=0;e<8;e++) v[e] = f2b(s[e]);
  *reinterpret_cast<bf16x8*>(dst + ((long)q*N + n)*32 + kkc*8) = v;
}

// ---- f32 transpose: dst[k][j] = src[j][k], src is [N][K] ----
__global__ void tr_f32(const float* __restrict__ src, float* __restrict__ dst,
                       int N, int K)
{
  const int id = blockIdx.x * blockDim.x + threadIdx.x;
  if (id >= N*K) return;
  const int k = id / N, j = id % N;
  dst[(long)k*N + j] = src[(long)j*K + k];
}

__global__ void bias_sum(const float* __restrict__ a, const float* __restrict__ b,
                         float* __restrict__ o, int n)
{
  const int i = blockIdx.x * blockDim.x + threadIdx.x;
  if (i < n) o[i] = a[i] + b[i];
}

// ---- embedding gather -> x bf16 [MPAD][256], zeros for pad rows ----
__global__ void embed_k(const int* __restrict__ ids, const float* __restrict__ emb,
                        bf16* __restrict__ x)
{
  const int tid = blockIdx.x * blockDim.x + threadIdx.x;   // MPAD*32 exact
  const int m = tid >> 5;
  const int c = (tid & 31) << 3;
  bf16x8 v;
  if (m < B_*T_) {
    const int id = ids[m];
    const float* e = emb + (long)id*E_ + c;
    #pragma unroll
    for (int j=0;j<8;j++) v[j] = f2b(e[j]);
  } else {
    #pragma unroll
    for (int j=0;j<8;j++) v[j] = f2b(0.f);
  }
  *reinterpret_cast<bf16x8*>(x + (long)m*256 + c) = v;
}

// ---- gates GEMM: G[m][1024] = A[m][256] @ Bp + bias, bf16 out ----
// R7: 256-VGPR budget + explicit dual-buffered B-fragment pipeline.
#define GLOADB_(dst, q_) { \
  _Pragma("unroll") \
  for (int ns=0; ns<8; ++ns) \
    dst[ns] = *reinterpret_cast<const bf16x8*>(bb + ((long)(q_)*NG + ns*16) * 32); }

#define GMFMAQ_(bfr, q_) { \
  bf16x8 af[4]; \
  _Pragma("unroll") \
  for (int ms=0; ms<4; ++ms) \
    af[ms] = *reinterpret_cast<const bf16x8*>(&smem[(ms*16 + l16)*264 + (q_)*32 + lg*8]); \
  _Pragma("unroll") \
  for (int ms=0; ms<4; ++ms) \
    _Pragma("unroll") \
    for (int ns=0; ns<8; ++ns) \
      acc[ms][ns] = __builtin_amdgcn_mfma_f32_16x16x32_bf16(af[ms], bfr[ns], acc[ms][ns], 0,0,0); }

__launch_bounds__(512, 2)
__global__ void gemm_gates(const bf16* __restrict__ A, const bf16* __restrict__ Bp,
                           const float* __restrict__ bias, bf16* __restrict__ Gout)
{
  __shared__ __align__(16) bf16 smem[17408];   // A: 64x264 ; epilogue stage: 8 x 16x136
  const int m0 = blockIdx.x * 64;
  const int tid = threadIdx.x;
  const int wave = tid >> 6;
  const int lane = tid & 63;
  const int l16 = lane & 15, lg = lane >> 4;

  for (int i = tid; i < 2048; i += 512){
    const int r = i >> 5, cc = (i & 31) << 3;
    *reinterpret_cast<bf16x8*>(&smem[r*264 + cc]) =
      *reinterpret_cast<const bf16x8*>(A + (long)(m0 + r)*256 + cc);
  }
  __syncthreads();

  f32x4 acc[4][8];
  #pragma unroll
  for (int ms=0; ms<4; ++ms)
    #pragma unroll
    for (int ns=0; ns<8; ++ns) acc[ms][ns] = f32x4{0.f,0.f,0.f,0.f};

  const bf16* bb = Bp + ((long)(wave*128 + l16) * 32 + lg*8);
  bf16x8 bA[8], bB[8];
  GLOADB_(bA, 0)
  #pragma unroll
  for (int h2=0; h2<4; ++h2){
    const int q0 = 2*h2;
    GLOADB_(bB, q0+1)
    GMFMAQ_(bA, q0)
    if (q0+2 < 8) GLOADB_(bA, q0+2)
    GMFMAQ_(bB, q0+1)
  }

  float bv[8];
  #pragma unroll
  for (int ns=0; ns<8; ++ns) bv[ns] = bias[wave*128 + ns*16 + l16];

  bf16* stage = smem + wave*2176;
  #pragma unroll
  for (int ms=0; ms<4; ++ms){
    __syncthreads();
    #pragma unroll
    for (int ns=0; ns<8; ++ns)
      #pragma unroll
      for (int r=0; r<4; ++r)
        stage[(lg*4 + r)*136 + ns*16 + l16] = f2b(acc[ms][ns][r] + bv[ns]);
    __syncthreads();
    const int row = lane >> 2, ch = lane & 3;
    bf16* gout = Gout + (long)(m0 + ms*16 + row)*NG + wave*128;
    #pragma unroll
    for (int cc2=0; cc2<4; ++cc2){
      const int chunk = ch + cc2*4;
      *reinterpret_cast<bf16x8*>(gout + chunk*8) =
        *reinterpret_cast<const bf16x8*>(&stage[row*136 + chunk*8]);
    }
  }
}

// ---- R7 persistent LSTM: 63 slices x 4 WGs, own-K in the wait window ----
#define LDB2(q_, off_) (*reinterpret_cast<const bf16x8*>(bb + ((long)(q_)*NG + (off_))*32))

__launch_bounds__(512, 2)
__global__ void lstm_x4(const bf16* __restrict__ G, const bf16* __restrict__ Bp,
                        bf16* __restrict__ Hout, unsigned* __restrict__ hX,
                        unsigned* __restrict__ flags)
{
  __shared__ __align__(16) bf16 hbuf[16*264];   // full h (16 x 256), padded
  __shared__ float gstage[256*17];               // gate partials [local col][row]
  const int bid = blockIdx.x;
  const int s = bid >> 2, g = bid & 3;
  const int b0 = s * 16;
  const int tid = threadIdx.x;
  const int wave = tid >> 6, lane = tid & 63;
  const int l16 = lane & 15, lg = lane >> 4;
  const int qd  = wave >> 1;               // gate quadrant of this wave
  const int h32 = (wave & 1) * 32;         // 32-col half within the 64

  const bf16* bb = Bp + ((long)(qd*256 + g*64 + h32 + l16) * 32 + lg*8);

  for (int i = tid; i < 16*264; i += 512) hbuf[i] = f2b(0.f);

  const int row = tid >> 5;            // 0..15
  const int k32 = tid & 31;
  const int j2  = k32 * 2;             // [0,64)
  float c0 = 0.f, c1 = 0.f;

  const long grow = (long)(b0 + row) * T_;
  const bf16* gptr = G + grow*NG + g*64 + j2;      // +{0,256,512,768}
  bf16*       hop  = Hout + grow*256 + g*64 + j2;

  unsigned* flag = flags + s*16;
  unsigned* hx0 = hX + (size_t)s*2048 + row*128 + g*32 + k32;
  unsigned* hx1 = hx0 + (size_t)NSLICE*2048;
  const unsigned* rb0 = hX + (size_t)s*2048 + row*128;
  const unsigned* rb1 = rb0 + (size_t)NSLICE*2048;

  const int qo0 = 2*g, qo1 = 2*g + 1;    // K-chunks covering own h-cols

  __syncthreads();

  // acc carries own-K(h_t) from iteration t's wait window into iteration
  // t+1, where remK completes gates(t+1). Pre-loop: h_{-1}=0 -> acc=0.
  f32x4 acc0 = {0.f,0.f,0.f,0.f}, acc1 = {0.f,0.f,0.f,0.f};
  bf16x8 f0[3], f1[3];   // 3-slot rotating remK prefetch (indices static)
  f0[0] = LDB2((qo0+2)&7, 0);  f1[0] = LDB2((qo0+2)&7, 16);
  f0[1] = LDB2((qo0+3)&7, 0);  f1[1] = LDB2((qo0+3)&7, 16);

  for (int t = 0; t < T_; ++t){
    // --- G prefetch (independent; consumed after B1) ---
    const bf16* gp = gptr + (long)t*NG;
    const unsigned vI = *reinterpret_cast<const unsigned*>(gp);
    const unsigned vF = *reinterpret_cast<const unsigned*>(gp + 256);
    const unsigned vG = *reinterpret_cast<const unsigned*>(gp + 512);
    const unsigned vO = *reinterpret_cast<const unsigned*>(gp + 768);

    // --- remK: the 6 K-chunks of sibling h-cols (3-slot pipeline) ---
    #pragma unroll
    for (int i = 0; i < 6; ++i){
      if (i < 4){
        const int qn = (qo0 + 4 + i) & 7;
        f0[(i+2)%3] = LDB2(qn, 0);
        f1[(i+2)%3] = LDB2(qn, 16);
      }
      const int qi = (qo0 + 2 + i) & 7;
      bf16x8 a = *reinterpret_cast<const bf16x8*>(&hbuf[l16*264 + qi*32 + lg*8]);
      acc0 = __builtin_amdgcn_mfma_f32_16x16x32_bf16(a, f0[i%3], acc0, 0,0,0);
      acc1 = __builtin_amdgcn_mfma_f32_16x16x32_bf16(a, f1[i%3], acc1, 0,0,0);
    }
    // dump gate partials, transposed [local col][17]
    {
      const int jj = wave*32 + l16;
      float* gc0 = &gstage[jj*17 + lg*4];
      gc0[0]=acc0[0]; gc0[1]=acc0[1]; gc0[2]=acc0[2]; gc0[3]=acc0[3];
      float* gc1 = &gstage[(jj+16)*17 + lg*4];
      gc1[0]=acc1[0]; gc1[1]=acc1[1]; gc1[2]=acc1[2]; gc1[3]=acc1[3];
    }
    __syncthreads();   // B1: gstage visible; hbuf reads done

    // --- elementwise: 2 h-cols per thread ---
    const float i0 = sigm (bflo(vI) + gstage[(j2      )*17 + row]);
    const float i1 = sigm (bfhi(vI) + gstage[(j2 +   1)*17 + row]);
    const float f0e = sigm (bflo(vF) + gstage[(j2 +  64)*17 + row]);
    const float f1e = sigm (bfhi(vF) + gstage[(j2 +  65)*17 + row]);
    const float g0e = tanh_(bflo(vG) + gstage[(j2 + 128)*17 + row]);
    const float g1e = tanh_(bfhi(vG) + gstage[(j2 + 129)*17 + row]);
    const float o0 = sigm (bflo(vO) + gstage[(j2 + 192)*17 + row]);
    const float o1 = sigm (bfhi(vO) + gstage[(j2 + 193)*17 + row]);
    c0 = f0e*c0 + i0*g0e;
    c1 = f1e*c1 + i1*g1e;
    const unsigned hw = packbf(o0*tanh_(c0), o1*tanh_(c1));

    // own block -> hbuf; publish -> LLC (relaxed sc1); Hout plain
    *reinterpret_cast<unsigned*>(&hbuf[row*264 + g*64 + j2]) = hw;
    __hip_atomic_store((t&1) ? hx1 : hx0, hw, __ATOMIC_RELAXED, __HIP_MEMORY_SCOPE_AGENT);
    *reinterpret_cast<unsigned*>(hop + (long)t*256) = hw;

    __syncthreads();   // B2: drains all stores (incl. hX publish)
    if (tid == 0)
      __hip_atomic_fetch_add(flag, 1u, __ATOMIC_RELAXED, __HIP_MEMORY_SCOPE_AGENT);

    // --- exchange-wait window: own-K MFMA over h_t + next-iter prefetch ---
    {
      bf16x8 o00 = LDB2(qo0, 0), o01 = LDB2(qo0, 16);
      bf16x8 o10 = LDB2(qo1, 0), o11 = LDB2(qo1, 16);
      f0[0] = LDB2((qo0+2)&7, 0);  f1[0] = LDB2((qo0+2)&7, 16);
      f0[1] = LDB2((qo0+3)&7, 0);  f1[1] = LDB2((qo0+3)&7, 16);
      acc0 = f32x4{0.f,0.f,0.f,0.f};
      acc1 = f32x4{0.f,0.f,0.f,0.f};
      bf16x8 a0 = *reinterpret_cast<const bf16x8*>(&hbuf[l16*264 + qo0*32 + lg*8]);
      acc0 = __builtin_amdgcn_mfma_f32_16x16x32_bf16(a0, o00, acc0, 0,0,0);
      acc1 = __builtin_amdgcn_mfma_f32_16x16x32_bf16(a0, o01, acc1, 0,0,0);
      bf16x8 a1 = *reinterpret_cast<const bf16x8*>(&hbuf[l16*264 + qo1*32 + lg*8]);
      acc0 = __builtin_amdgcn_mfma_f32_16x16x32_bf16(a1, o10, acc0, 0,0,0);
      acc1 = __builtin_amdgcn_mfma_f32_16x16x32_bf16(a1, o11, acc1, 0,0,0);
    }

    // --- wait all 4 WGs of this slice, then pull siblings' h-blocks ---
    {
      const unsigned tgt = 4u*(t+1);
      if (lane == 0){
        int guard = 0;
        while (__hip_atomic_load(flag, __ATOMIC_RELAXED, __HIP_MEMORY_SCOPE_AGENT) < tgt
               && ++guard < (1<<20))
          __builtin_amdgcn_s_sleep(1);
      }
      asm volatile("" ::: "memory");
      __builtin_amdgcn_sched_barrier(0);
      const unsigned* rb = (t&1) ? rb1 : rb0;
      #pragma unroll
      for (int sb=1; sb<4; ++sb){
        const int g2 = (g + sb) & 3;
        const unsigned w = __hip_atomic_load(rb + g2*32 + k32,
                                             __ATOMIC_RELAXED, __HIP_MEMORY_SCOPE_AGENT);
        *reinterpret_cast<unsigned*>(&hbuf[row*264 + g2*64 + j2]) = w;
      }
    }
    __syncthreads();   // B3: hbuf complete for next step
  }
}

// ---- fused attention GEMM + softmax + applied (w*x) + flat bf16 ----
__launch_bounds__(256)
__global__ void attn_applied(const bf16* __restrict__ H2, const bf16* __restrict__ Wap,
                             const float* __restrict__ battn, const int* __restrict__ ids,
                             const float* __restrict__ emb, float* __restrict__ applied,
                             bf16* __restrict__ flat)
{
  __shared__ __align__(16) bf16 albuf[32*264];
  __shared__ float sbuf[32*257];
  const int mt = blockIdx.x, t = blockIdx.y;
  const int b0 = mt*32;
  const int tid = threadIdx.x;
  const int wave = tid >> 6, lane = tid & 63;
  const int l16 = lane & 15, lg = lane >> 4;

  for (int i = tid; i < 1024; i += 256){
    const int r = i >> 5, cc = (i & 31) << 3;
    const int b = b0 + r;
    bf16x8 v;
    if (b < B_) v = *reinterpret_cast<const bf16x8*>(H2 + ((long)b*T_ + t)*256 + cc);
    else { 
      #pragma unroll
      for (int j=0;j<8;j++) v[j] = f2b(0.f);
    }
    *reinterpret_cast<bf16x8*>(&albuf[r*264 + cc]) = v;
  }
  __syncthreads();

  f32x4 acc[2][4];
  #pragma unroll
  for (int ms=0; ms<2; ++ms)
    #pragma unroll
    for (int ns=0; ns<4; ++ns) acc[ms][ns] = f32x4{0.f,0.f,0.f,0.f};

  const bf16* bb = Wap + (long)t*65536 + ((long)(wave*64 + l16) * 32 + lg*8);
  #pragma unroll 2
  for (int q=0; q<8; ++q){
    bf16x8 a0 = *reinterpret_cast<const bf16x8*>(&albuf[l16*264 + q*32 + lg*8]);
    bf16x8 a1 = *reinterpret_cast<const bf16x8*>(&albuf[(16 + l16)*264 + q*32 + lg*8]);
    #pragma unroll
    for (int ns=0; ns<4; ++ns){
      bf16x8 b = *reinterpret_cast<const bf16x8*>(bb + ((long)q*256 + ns*16) * 32);
      acc[0][ns] = __builtin_amdgcn_mfma_f32_16x16x32_bf16(a0, b, acc[0][ns], 0,0,0);
      acc[1][ns] = __builtin_amdgcn_mfma_f32_16x16x32_bf16(a1, b, acc[1][ns], 0,0,0);
    }
  }
  float bv[4];
  #pragma unroll
  for (int ns=0; ns<4; ++ns) bv[ns] = battn[t*256 + wave*64 + ns*16 + l16];
  #pragma unroll
  for (int ms=0; ms<2; ++ms)
    #pragma unroll
    for (int ns=0; ns<4; ++ns)
      #pragma unroll
      for (int r=0; r<4; ++r)
        sbuf[(ms*16 + lg*4 + r)*257 + wave*64 + ns*16 + l16] = acc[ms][ns][r] + bv[ns];
  __syncthreads();

  const int row = tid >> 3, seg = tid & 7;
  const float* srow = &sbuf[row*257 + seg*32];
  float v[32];
  float mx = -1e30f;
  #pragma unroll
  for (int i=0;i<32;++i){ v[i] = srow[i]; mx = fmaxf(mx, v[i]); }
  #pragma unroll
  for (int off=1; off<8; off<<=1) mx = fmaxf(mx, __shfl_xor(mx, off));
  float s = 0.f;
  #pragma unroll
  for (int i=0;i<32;++i){ v[i] = __expf(v[i] - mx); s += v[i]; }
  #pragma unroll
  for (int off=1; off<8; off<<=1) s += __shfl_xor(s, off);
  const float inv = 1.f / s;
  const int b = b0 + row;
  if (b < B_){
    const int id = ids[b*T_ + t];
    const float* ex = emb + (long)id*256 + seg*32;
    float* ap = applied + ((long)b*T_ + t)*256 + seg*32;
    bf16* fp = flat + (long)b*25856 + t*256 + seg*32;
    #pragma unroll
    for (int i=0;i<32;++i){
      const float val = v[i]*inv*ex[i];
      ap[i] = val;
      fp[i] = f2b(val);
    }
  }
}

// ---- W1 GEMM: part[ks][m][n] = flat[m][ks-slice] @ W1p, K-split 8 ----
__launch_bounds__(512)
__global__ void gemm_mlp1(const bf16* __restrict__ A, const bf16* __restrict__ Bp,
                          float* __restrict__ part)
{
  const int m0 = blockIdx.x * 32;
  const int ks = blockIdx.y;
  const int tid = threadIdx.x;
  const int wave = tid >> 6, lane = tid & 63;
  const int l16 = lane & 15, lg = lane >> 4;
  f32x4 acc[2][4];
  #pragma unroll
  for (int ms=0; ms<2; ++ms)
    #pragma unroll
    for (int ns=0; ns<4; ++ns) acc[ms][ns] = f32x4{0.f,0.f,0.f,0.f};

  const bf16* arow0 = A + (long)(m0 + l16)*25856 + lg*8;
  const bf16* arow1 = A + (long)(m0 + 16 + l16)*25856 + lg*8;
  const bf16* bb = Bp + ((long)(wave*64 + l16) * 32 + lg*8);
  #pragma unroll 2
  for (int q = ks*101; q < ks*101 + 101; ++q){
    bf16x8 a0 = *reinterpret_cast<const bf16x8*>(arow0 + (long)q*32);
    bf16x8 a1 = *reinterpret_cast<const bf16x8*>(arow1 + (long)q*32);
    #pragma unroll
    for (int ns=0; ns<4; ++ns){
      bf16x8 b = *reinterpret_cast<const bf16x8*>(bb + ((long)q*512 + ns*16) * 32);
      acc[0][ns] = __builtin_amdgcn_mfma_f32_16x16x32_bf16(a0, b, acc[0][ns], 0,0,0);
      acc[1][ns] = __builtin_amdgcn_mfma_f32_16x16x32_bf16(a1, b, acc[1][ns], 0,0,0);
    }
  }
  #pragma unroll
  for (int ms=0; ms<2; ++ms)
    #pragma unroll
    for (int ns=0; ns<4; ++ns)
      #pragma unroll
      for (int r=0; r<4; ++r)
        part[((long)ks*1024 + m0 + ms*16 + lg*4 + r)*512 + wave*64 + ns*16 + l16] = acc[ms][ns][r];
}

__global__ void reduce_relu(const float* __restrict__ part, const float* __restrict__ b1,
                            float* __restrict__ d1)
{
  const int idx = blockIdx.x*256 + threadIdx.x;   // 524288 exact
  const int n = idx & 511, m = idx >> 9;
  float s = b1[n];
  #pragma unroll
  for (int k=0;k<8;k++) s += part[((long)k*1024 + m)*512 + n];
  d1[idx] = fmaxf(s, 0.f);
}

// ---- MLP layers 2..4 fused, one block per batch row ----
__launch_bounds__(128)
__global__ void mlp_tail(const float* __restrict__ d1, const float* __restrict__ W2T,
                         const float* __restrict__ b2, const float* __restrict__ W3T,
                         const float* __restrict__ b3, const float* __restrict__ Wout,
                         const float* __restrict__ bout, float* __restrict__ tag)
{
  __shared__ float r1[512];
  __shared__ float r2[128];
  __shared__ float r3[64];
  const int b = blockIdx.x;
  const int tid = threadIdx.x;
  for (int i = tid; i < 512; i += 128) r1[i] = d1[(long)b*512 + i];
  __syncthreads();
  float a = b2[tid];
  #pragma unroll 8
  for (int k=0;k<512;++k) a += W2T[k*128 + tid] * r1[k];
  r2[tid] = fmaxf(a, 0.f);
  __syncthreads();
  if (tid < 64){
    float a3 = b3[tid];
    #pragma unroll 8
    for (int k=0;k<128;++k) a3 += W3T[k*64 + tid] * r2[k];
    r3[tid] = fmaxf(a3, 0.f);
  }
  __syncthreads();
  if (tid < 64){
    float p = r3[tid] * Wout[tid];
    #pragma unroll
    for (int off=1; off<64; off<<=1) p += __shfl_xor(p, off);
    if (tid == 0) tag[b] = p + bout[0];
  }
}

extern "C" void kernel_launch(void* const* d_in, const int* in_sizes, int n_in,
                              void* d_out, int out_size, void* d_ws, size_t ws_size,
                              hipStream_t stream)
{
  const int*   ids   = (const int*)  d_in[0];
  const float* emb   = (const float*)d_in[1];
  const float* Wih1  = (const float*)d_in[2];
  const float* Whh1  = (const float*)d_in[3];
  const float* bih1  = (const float*)d_in[4];
  const float* bhh1  = (const float*)d_in[5];
  const float* Wih2  = (const float*)d_in[6];
  const float* Whh2  = (const float*)d_in[7];
  const float* bih2  = (const float*)d_in[8];
  const float* bhh2  = (const float*)d_in[9];
  const float* Wattn = (const float*)d_in[10];
  const float* battn = (const float*)d_in[11];
  const float* W1    = (const float*)d_in[12];
  const float* b1    = (const float*)d_in[13];
  const float* W2    = (const float*)d_in[14];
  const float* b2    = (const float*)d_in[15];
  const float* W3    = (const float*)d_in[16];
  const float* b3    = (const float*)d_in[17];
  const float* Wout  = (const float*)d_in[18];
  const float* bout  = (const float*)d_in[19];
  float* out = (float*)d_out;
  char*  ws  = (char*)d_ws;

  // workspace layout (bytes)
  constexpr size_t OW_IH1 = 0;
  constexpr size_t OW_HH1 = 524288;
  constexpr size_t OW_IH2 = 1048576;
  constexpr size_t OW_HH2 = 1572864;
  constexpr size_t OW_ATT = 2097152;     // 13,238,272
  constexpr size_t OW_W1  = 15335424;    // 26,476,544
  constexpr size_t OW_W2T = 41811968;
  constexpr size_t OW_W3T = 42074112;
  constexpr size_t OB1    = 42106880;
  constexpr size_t OB2    = 42110976;
  constexpr size_t OXH2   = 42115072;    // x bf16, later h2 (alias)
  constexpr size_t OG     = 94248960;    // gates (208.5MB); later flat+part alias
  constexpr size_t OFLAT  = OG;
  constexpr size_t OPART  = OG + 52953088;
  constexpr size_t OH1    = 302784512;
  constexpr size_t OD1    = 354918400;   // d1 (2MB) — dead during LSTMs:
  constexpr size_t OHX    = OD1;         //   hX: 2 parity x 63 x 8KB = 1,032,192
  constexpr size_t OFLG   = OD1 + 1032192; // flags: 2 layers x 4KB
  constexpr size_t NEED   = 357015552;
  if (ws_size < NEED) return;

  bf16*  pIH1 = (bf16*) (ws + OW_IH1);
  bf16*  pHH1 = (bf16*) (ws + OW_HH1);
  bf16*  pIH2 = (bf16*) (ws + OW_IH2);
  bf16*  pHH2 = (bf16*) (ws + OW_HH2);
  bf16*  pATT = (bf16*) (ws + OW_ATT);
  bf16*  pW1  = (bf16*) (ws + OW_W1);
  float* pW2T = (float*)(ws + OW_W2T);
  float* pW3T = (float*)(ws + OW_W3T);
  float* pB1  = (float*)(ws + OB1);
  float* pB2  = (float*)(ws + OB2);
  bf16*  pXH2 = (bf16*) (ws + OXH2);
  bf16*  pG   = (bf16*) (ws + OG);
  bf16*  pFLAT= (bf16*) (ws + OFLAT);
  float* pPART= (float*)(ws + OPART);
  bf16*  pH1  = (bf16*) (ws + OH1);
  float* pD1  = (float*)(ws + OD1);
  unsigned* pHX  = (unsigned*)(ws + OHX);
  unsigned* pFL1 = (unsigned*)(ws + OFLG);
  unsigned* pFL2 = (unsigned*)(ws + OFLG + 4096);

  // zero h1 pad tail (rows 101808..101823) before g2 GEMM reads it
  hipMemsetAsync(ws + OH1 + (size_t)101808*512, 0, (size_t)16*512, stream);
  // zero exchange flags for both LSTM layers (graph-replay safe)
  hipMemsetAsync(ws + OFLG, 0, 8192, stream);

  // weight packing
  pack_bT<<<dim3(128),        256, 0, stream>>>(Wih1,  pIH1, 1024, 256);
  pack_bT<<<dim3(128),        256, 0, stream>>>(Whh1,  pHH1, 1024, 256);
  pack_bT<<<dim3(128),        256, 0, stream>>>(Wih2,  pIH2, 1024, 256);
  pack_bT<<<dim3(128),        256, 0, stream>>>(Whh2,  pHH2, 1024, 256);
  pack_bT<<<dim3(32, 101),    256, 0, stream>>>(Wattn, pATT, 256,  256);
  pack_bT<<<dim3(6464),       256, 0, stream>>>(W1,    pW1,  512,  25856);
  tr_f32 <<<dim3(256),        256, 0, stream>>>(W2, pW2T, 128, 512);
  tr_f32 <<<dim3(32),         256, 0, stream>>>(W3, pW3T, 64, 128);
  bias_sum<<<dim3(4),         256, 0, stream>>>(bih1, bhh1, pB1, 1024);
  bias_sum<<<dim3(4),         256, 0, stream>>>(bih2, bhh2, pB2, 1024);

  // embed -> x bf16
  embed_k<<<dim3(12728), 256, 0, stream>>>(ids, emb, pXH2);

  // layer 1
  gemm_gates<<<dim3(1591), 512, 0, stream>>>(pXH2, pIH1, pB1, pG);
  lstm_x4   <<<dim3(252),  512, 0, stream>>>(pG, pHH1, pH1, pHX, pFL1);
  // layer 2
  gemm_gates<<<dim3(1591), 512, 0, stream>>>(pH1, pIH2, pB2, pG);
  lstm_x4   <<<dim3(252),  512, 0, stream>>>(pG, pHH2, pXH2, pHX, pFL2);

  // flat pad rows [1000,1024) zero (after gates buffer is dead)
  hipMemsetAsync(ws + OFLAT + (size_t)B_*25856*2, 0, (size_t)24*25856*2, stream);

  // attention + softmax + applied (writes d_out applied region + flat bf16)
  attn_applied<<<dim3(32, 101), 256, 0, stream>>>(pXH2, pATT, battn, ids, emb,
                                                  out + 1000, pFLAT);

  // MLP
  gemm_mlp1  <<<dim3(32, 8), 512, 0, stream>>>(pFLAT, pW1, pPART);
  reduce_relu<<<dim3(2048),  256, 0, stream>>>(pPART, b1, pD1);
  mlp_tail   <<<dim3(1000),  128, 0, stream>>>(pD1, pW2T, b2, pW3T, b3, Wout, bout, out);
}

// Round 9
// 862.805 us; speedup vs baseline: 4.9715x; 1.3205x over previous
//
#include <hip/hip_runtime.h>
#include <hip/hip_bf16.h>

// AttnDecoderRNN on MI355X.
// R6: 4-way col-split LSTM, 252 WGs, pure-LLC relaxed exchange (348 us).
// R7: own-K MFMA in exchange-wait window (316 us/layer).
// R8: FUSE gates GEMM into the LSTM. gates = x@Wih^T + h@Whh^T + b
//     computed per step: Wih quarter (128KB) streams from L2 like Whh;
//     x_{t+1} prefetched from HBM -> LDS xbuf; all x-K MFMAs run inside
//     the exchange-wait window (sibling-independent). Eliminates both
//     gemm_gates kernels and the 208MB/layer G write + read.

#define B_    1000
#define T_    101
#define E_    256
#define H_    256
#define BPAD  1008      // 63 * 16
#define MPAD  101824    // 1591 * 64  >= BPAD*T_ = 101808
#define NG    1024      // 4H
#define NSLICE 63

typedef __bf16 bf16;
typedef __bf16 bf16x8 __attribute__((ext_vector_type(8)));
typedef float  f32x4  __attribute__((ext_vector_type(4)));

__device__ __forceinline__ bf16 f2b(float f){
  unsigned u = __builtin_bit_cast(unsigned, f);
  u += 0x7FFFu + ((u >> 16) & 1u);               // RNE
  unsigned short h = (unsigned short)(u >> 16);
  return __builtin_bit_cast(bf16, h);
}
__device__ __forceinline__ float b2f(bf16 v){
  unsigned short s = __builtin_bit_cast(unsigned short, v);
  unsigned u = ((unsigned)s) << 16;
  return __builtin_bit_cast(float, u);
}
__device__ __forceinline__ unsigned packbf(float a, float b){
  unsigned ua = __builtin_bit_cast(unsigned, a);
  ua += 0x7FFFu + ((ua >> 16) & 1u);
  unsigned ub = __builtin_bit_cast(unsigned, b);
  ub += 0x7FFFu + ((ub >> 16) & 1u);
  return (ua >> 16) | (ub & 0xffff0000u);
}
__device__ __forceinline__ float sigm(float x){ return 1.f/(1.f + __expf(-x)); }
__device__ __forceinline__ float tanh_(float x){ return 2.f/(1.f + __expf(-2.f*x)) - 1.f; }

// ---- pack W[N][K] f32 -> Bp[K/32][N][32] bf16 (MFMA B-fragment order) ----
__global__ void pack_bT(const float* __restrict__ src, bf16* __restrict__ dst,
                        int N, int K)
{
  const long batch = blockIdx.y;
  src += batch * (long)N * K;
  dst += batch * (long)(K/32) * N * 32;
  const int tid = blockIdx.x * blockDim.x + threadIdx.x;
  const int total = (K/32) * N * 4;
  if (tid >= total) return;
  const int kkc = tid & 3;
  const int rem = tid >> 2;
  const int n = rem % N;
  const int q = rem / N;
  const float* s = src + (long)n*K + q*32 + kkc*8;
  bf16x8 v;
  #pragma unroll
  for (int e=0;e<8;e++) v[e] = f2b(s[e]);
  *reinterpret_cast<bf16x8*>(dst + ((long)q*N + n)*32 + kkc*8) = v;
}

// ---- f32 transpose: dst[k][j] = src[j][k], src is [N][K] ----
__global__ void tr_f32(const float* __restrict__ src, float* __restrict__ dst,
                       int N, int K)
{
  const int id = blockIdx.x * blockDim.x + threadIdx.x;
  if (id >= N*K) return;
  const int k = id / N, j = id % N;
  dst[(long)k*N + j] = src[(long)j*K + k];
}

__global__ void bias_sum(const float* __restrict__ a, const float* __restrict__ b,
                         float* __restrict__ o, int n)
{
  const int i = blockIdx.x * blockDim.x + threadIdx.x;
  if (i < n) o[i] = a[i] + b[i];
}

// ---- embedding gather -> x bf16 [MPAD][256], zeros for pad rows ----
__global__ void embed_k(const int* __restrict__ ids, const float* __restrict__ emb,
                        bf16* __restrict__ x)
{
  const int tid = blockIdx.x * blockDim.x + threadIdx.x;   // MPAD*32 exact
  const int m = tid >> 5;
  const int c = (tid & 31) << 3;
  bf16x8 v;
  if (m < B_*T_) {
    const int id = ids[m];
    const float* e = emb + (long)id*E_ + c;
    #pragma unroll
    for (int j=0;j<8;j++) v[j] = f2b(e[j]);
  } else {
    #pragma unroll
    for (int j=0;j<8;j++) v[j] = f2b(0.f);
  }
  *reinterpret_cast<bf16x8*>(x + (long)m*256 + c) = v;
}

// ---- R8 fused LSTM: 63 slices x 4 WGs; gates GEMM fused ----
#define MF(a,b,c) __builtin_amdgcn_mfma_f32_16x16x32_bf16((a),(b),(c),0,0,0)
#define LDW(q_,off_)  (*reinterpret_cast<const bf16x8*>(bbW + ((long)(q_)*NG + (off_))*32))
#define LDX8(q_,off_) (*reinterpret_cast<const bf16x8*>(bbX + ((long)(q_)*NG + (off_))*32))

// full x-K (8 chunks of Wih), dual-buffered; accumulates into acc0/acc1
#define XK_ALL() { \
  bf16x8 xA0 = LDX8(0,0), xA1 = LDX8(0,16), xB0, xB1; \
  _Pragma("unroll") \
  for (int h2x=0; h2x<4; ++h2x){ \
    const int q0x = 2*h2x; \
    xB0 = LDX8(q0x+1,0); xB1 = LDX8(q0x+1,16); \
    { bf16x8 ax = *reinterpret_cast<const bf16x8*>(&xbuf[l16*264 + q0x*32 + lg*8]); \
      acc0 = MF(ax,xA0,acc0); acc1 = MF(ax,xA1,acc1); } \
    if (q0x+2 < 8){ xA0 = LDX8(q0x+2,0); xA1 = LDX8(q0x+2,16); } \
    { bf16x8 ax = *reinterpret_cast<const bf16x8*>(&xbuf[l16*264 + (q0x+1)*32 + lg*8]); \
      acc0 = MF(ax,xB0,acc0); acc1 = MF(ax,xB1,acc1); } \
  } }

__launch_bounds__(512, 2)
__global__ void lstm_fused(const bf16* __restrict__ X, const bf16* __restrict__ Wihp,
                           const bf16* __restrict__ Whhp, const float* __restrict__ bias,
                           bf16* __restrict__ Hout, unsigned* __restrict__ hX,
                           unsigned* __restrict__ flags)
{
  __shared__ __align__(16) bf16 hbuf[16*264];   // h_{t-1}/h_t (16 x 256, padded)
  __shared__ __align__(16) bf16 xbuf[16*264];   // x_t / x_{t+1}
  __shared__ float gstage[256*17];               // gate partials [local col][row]
  const int bid = blockIdx.x;
  const int s = bid >> 2, g = bid & 3;
  const int b0 = s * 16;
  const int tid = threadIdx.x;
  const int wave = tid >> 6, lane = tid & 63;
  const int l16 = lane & 15, lg = lane >> 4;
  const int qd  = wave >> 1;               // gate quadrant of this wave
  const int h32 = (wave & 1) * 32;         // 32-col half within the 64

  const bf16* bbW = Whhp + ((long)(qd*256 + g*64 + h32 + l16) * 32 + lg*8);
  const bf16* bbX = Wihp + ((long)(qd*256 + g*64 + h32 + l16) * 32 + lg*8);

  const int row = tid >> 5;            // 0..15
  const int k32 = tid & 31;
  const int j2  = k32 * 2;             // [0,64)
  float c0 = 0.f, c1 = 0.f;

  const long grow = (long)(b0 + row) * T_;
  const bf16* xp  = X    + grow*256 + k32*8;   // 16B x-slice per thread
  bf16*       hop = Hout + grow*256 + g*64 + j2;

  // combined bias -> 8 registers
  const float bvi0 = bias[      g*64 + j2    ];
  const float bvi1 = bias[      g*64 + j2 + 1];
  const float bvf0 = bias[256 + g*64 + j2    ];
  const float bvf1 = bias[256 + g*64 + j2 + 1];
  const float bvg0 = bias[512 + g*64 + j2    ];
  const float bvg1 = bias[512 + g*64 + j2 + 1];
  const float bvo0 = bias[768 + g*64 + j2    ];
  const float bvo1 = bias[768 + g*64 + j2 + 1];

  unsigned* flag = flags + s*16;
  unsigned* hx0 = hX + (size_t)s*2048 + row*128 + g*32 + k32;
  unsigned* hx1 = hx0 + (size_t)NSLICE*2048;
  const unsigned* rb0 = hX + (size_t)s*2048 + row*128;
  const unsigned* rb1 = rb0 + (size_t)NSLICE*2048;

  const int qo0 = 2*g, qo1 = 2*g + 1;    // Whh K-chunks covering own h-cols

  for (int i = tid; i < 16*264; i += 512) hbuf[i] = f2b(0.f);
  *reinterpret_cast<bf16x8*>(&xbuf[row*264 + k32*8]) =
      *reinterpret_cast<const bf16x8*>(xp);          // x_0
  __syncthreads();

  // prologue: acc = x-K(x_0); h_{-1}=0 so own-K contributes nothing
  f32x4 acc0 = {0.f,0.f,0.f,0.f}, acc1 = {0.f,0.f,0.f,0.f};
  XK_ALL();
  bf16x8 f0[3], f1[3];   // 3-slot rotating remK (Whh sibling chunks)
  f0[0] = LDW((qo0+2)&7, 0);  f1[0] = LDW((qo0+2)&7, 16);
  f0[1] = LDW((qo0+3)&7, 0);  f1[1] = LDW((qo0+3)&7, 16);

  for (int t = 0; t < T_; ++t){
    // x_{t+1} prefetch (HBM; consumed at the LDS write after elementwise)
    const bf16x8 xreg = *reinterpret_cast<const bf16x8*>(xp + (long)(t+1)*256);

    // --- remK: 6 Whh chunks over sibling h-cols of h_{t-1} ---
    #pragma unroll
    for (int i = 0; i < 6; ++i){
      if (i < 4){
        const int qn = (qo0 + 4 + i) & 7;
        f0[(i+2)%3] = LDW(qn, 0);
        f1[(i+2)%3] = LDW(qn, 16);
      }
      const int qi = (qo0 + 2 + i) & 7;
      bf16x8 a = *reinterpret_cast<const bf16x8*>(&hbuf[l16*264 + qi*32 + lg*8]);
      acc0 = MF(a, f0[i%3], acc0);
      acc1 = MF(a, f1[i%3], acc1);
    }
    // dump gate partials, transposed [local col][17]
    {
      const int jj = wave*32 + l16;
      float* gc0 = &gstage[jj*17 + lg*4];
      gc0[0]=acc0[0]; gc0[1]=acc0[1]; gc0[2]=acc0[2]; gc0[3]=acc0[3];
      float* gc1 = &gstage[(jj+16)*17 + lg*4];
      gc1[0]=acc1[0]; gc1[1]=acc1[1]; gc1[2]=acc1[2]; gc1[3]=acc1[3];
    }
    __syncthreads();   // B1: gstage visible; hbuf/xbuf reads done

    // --- elementwise: 2 h-cols per thread ---
    const float i0 = sigm (bvi0 + gstage[(j2      )*17 + row]);
    const float i1 = sigm (bvi1 + gstage[(j2 +   1)*17 + row]);
    const float f0e= sigm (bvf0 + gstage[(j2 +  64)*17 + row]);
    const float f1e= sigm (bvf1 + gstage[(j2 +  65)*17 + row]);
    const float g0e= tanh_(bvg0 + gstage[(j2 + 128)*17 + row]);
    const float g1e= tanh_(bvg1 + gstage[(j2 + 129)*17 + row]);
    const float o0 = sigm (bvo0 + gstage[(j2 + 192)*17 + row]);
    const float o1 = sigm (bvo1 + gstage[(j2 + 193)*17 + row]);
    c0 = f0e*c0 + i0*g0e;
    c1 = f1e*c1 + i1*g1e;
    const unsigned hw = packbf(o0*tanh_(c0), o1*tanh_(c1));

    // own h -> hbuf; x_{t+1} -> xbuf; publish h -> LLC; Hout
    *reinterpret_cast<unsigned*>(&hbuf[row*264 + g*64 + j2]) = hw;
    *reinterpret_cast<bf16x8*>(&xbuf[row*264 + k32*8]) = xreg;
    __hip_atomic_store((t&1) ? hx1 : hx0, hw, __ATOMIC_RELAXED, __HIP_MEMORY_SCOPE_AGENT);
    *reinterpret_cast<unsigned*>(hop + (long)t*256) = hw;

    __syncthreads();   // B2: drains all stores (incl. hX publish)
    if (tid == 0)
      __hip_atomic_fetch_add(flag, 1u, __ATOMIC_RELAXED, __HIP_MEMORY_SCOPE_AGENT);

    // --- wait window: own-K(h_t) + full x-K(x_{t+1}) — sibling-independent ---
    {
      bf16x8 o00 = LDW(qo0, 0), o01 = LDW(qo0, 16);
      bf16x8 o10 = LDW(qo1, 0), o11 = LDW(qo1, 16);
      acc0 = f32x4{0.f,0.f,0.f,0.f};
      acc1 = f32x4{0.f,0.f,0.f,0.f};
      bf16x8 a0 = *reinterpret_cast<const bf16x8*>(&hbuf[l16*264 + qo0*32 + lg*8]);
      acc0 = MF(a0, o00, acc0); acc1 = MF(a0, o01, acc1);
      bf16x8 a1 = *reinterpret_cast<const bf16x8*>(&hbuf[l16*264 + qo1*32 + lg*8]);
      acc0 = MF(a1, o10, acc0); acc1 = MF(a1, o11, acc1);
      XK_ALL();
      f0[0] = LDW((qo0+2)&7, 0);  f1[0] = LDW((qo0+2)&7, 16);
      f0[1] = LDW((qo0+3)&7, 0);  f1[1] = LDW((qo0+3)&7, 16);
    }

    // --- wait all 4 WGs of this slice, then pull siblings' h-blocks ---
    {
      const unsigned tgt = 4u*(t+1);
      if (lane == 0){
        int guard = 0;
        while (__hip_atomic_load(flag, __ATOMIC_RELAXED, __HIP_MEMORY_SCOPE_AGENT) < tgt
               && ++guard < (1<<20))
          __builtin_amdgcn_s_sleep(1);
      }
      asm volatile("" ::: "memory");
      __builtin_amdgcn_sched_barrier(0);
      const unsigned* rb = (t&1) ? rb1 : rb0;
      #pragma unroll
      for (int sb=1; sb<4; ++sb){
        const int g2 = (g + sb) & 3;
        const unsigned w = __hip_atomic_load(rb + g2*32 + k32,
                                             __ATOMIC_RELAXED, __HIP_MEMORY_SCOPE_AGENT);
        *reinterpret_cast<unsigned*>(&hbuf[row*264 + g2*64 + j2]) = w;
      }
    }
    __syncthreads();   // B3: hbuf complete for next step
  }
}

// ---- fused attention GEMM + softmax + applied (w*x) + flat bf16 ----
__launch_bounds__(256)
__global__ void attn_applied(const bf16* __restrict__ H2, const bf16* __restrict__ Wap,
                             const float* __restrict__ battn, const int* __restrict__ ids,
                             const float* __restrict__ emb, float* __restrict__ applied,
                             bf16* __restrict__ flat)
{
  __shared__ __align__(16) bf16 albuf[32*264];
  __shared__ float sbuf[32*257];
  const int mt = blockIdx.x, t = blockIdx.y;
  const int b0 = mt*32;
  const int tid = threadIdx.x;
  const int wave = tid >> 6, lane = tid & 63;
  const int l16 = lane & 15, lg = lane >> 4;

  for (int i = tid; i < 1024; i += 256){
    const int r = i >> 5, cc = (i & 31) << 3;
    const int b = b0 + r;
    bf16x8 v;
    if (b < B_) v = *reinterpret_cast<const bf16x8*>(H2 + ((long)b*T_ + t)*256 + cc);
    else { 
      #pragma unroll
      for (int j=0;j<8;j++) v[j] = f2b(0.f);
    }
    *reinterpret_cast<bf16x8*>(&albuf[r*264 + cc]) = v;
  }
  __syncthreads();

  f32x4 acc[2][4];
  #pragma unroll
  for (int ms=0; ms<2; ++ms)
    #pragma unroll
    for (int ns=0; ns<4; ++ns) acc[ms][ns] = f32x4{0.f,0.f,0.f,0.f};

  const bf16* bb = Wap + (long)t*65536 + ((long)(wave*64 + l16) * 32 + lg*8);
  #pragma unroll 2
  for (int q=0; q<8; ++q){
    bf16x8 a0 = *reinterpret_cast<const bf16x8*>(&albuf[l16*264 + q*32 + lg*8]);
    bf16x8 a1 = *reinterpret_cast<const bf16x8*>(&albuf[(16 + l16)*264 + q*32 + lg*8]);
    #pragma unroll
    for (int ns=0; ns<4; ++ns){
      bf16x8 b = *reinterpret_cast<const bf16x8*>(bb + ((long)q*256 + ns*16) * 32);
      acc[0][ns] = __builtin_amdgcn_mfma_f32_16x16x32_bf16(a0, b, acc[0][ns], 0,0,0);
      acc[1][ns] = __builtin_amdgcn_mfma_f32_16x16x32_bf16(a1, b, acc[1][ns], 0,0,0);
    }
  }
  float bv[4];
  #pragma unroll
  for (int ns=0; ns<4; ++ns) bv[ns] = battn[t*256 + wave*64 + ns*16 + l16];
  #pragma unroll
  for (int ms=0; ms<2; ++ms)
    #pragma unroll
    for (int ns=0; ns<4; ++ns)
      #pragma unroll
      for (int r=0; r<4; ++r)
        sbuf[(ms*16 + lg*4 + r)*257 + wave*64 + ns*16 + l16] = acc[ms][ns][r] + bv[ns];
  __syncthreads();

  const int row = tid >> 3, seg = tid & 7;
  const float* srow = &sbuf[row*257 + seg*32];
  float v[32];
  float mx = -1e30f;
  #pragma unroll
  for (int i=0;i<32;++i){ v[i] = srow[i]; mx = fmaxf(mx, v[i]); }
  #pragma unroll
  for (int off=1; off<8; off<<=1) mx = fmaxf(mx, __shfl_xor(mx, off));
  float s = 0.f;
  #pragma unroll
  for (int i=0;i<32;++i){ v[i] = __expf(v[i] - mx); s += v[i]; }
  #pragma unroll
  for (int off=1; off<8; off<<=1) s += __shfl_xor(s, off);
  const float inv = 1.f / s;
  const int b = b0 + row;
  if (b < B_){
    const int id = ids[b*T_ + t];
    const float* ex = emb + (long)id*256 + seg*32;
    float* ap = applied + ((long)b*T_ + t)*256 + seg*32;
    bf16* fp = flat + (long)b*25856 + t*256 + seg*32;
    #pragma unroll
    for (int i=0;i<32;++i){
      const float val = v[i]*inv*ex[i];
      ap[i] = val;
      fp[i] = f2b(val);
    }
  }
}

// ---- W1 GEMM: part[ks][m][n] = flat[m][ks-slice] @ W1p, K-split 8 ----
__launch_bounds__(512)
__global__ void gemm_mlp1(const bf16* __restrict__ A, const bf16* __restrict__ Bp,
                          float* __restrict__ part)
{
  const int m0 = blockIdx.x * 32;
  const int ks = blockIdx.y;
  const int tid = threadIdx.x;
  const int wave = tid >> 6, lane = tid & 63;
  const int l16 = lane & 15, lg = lane >> 4;
  f32x4 acc[2][4];
  #pragma unroll
  for (int ms=0; ms<2; ++ms)
    #pragma unroll
    for (int ns=0; ns<4; ++ns) acc[ms][ns] = f32x4{0.f,0.f,0.f,0.f};

  const bf16* arow0 = A + (long)(m0 + l16)*25856 + lg*8;
  const bf16* arow1 = A + (long)(m0 + 16 + l16)*25856 + lg*8;
  const bf16* bb = Bp + ((long)(wave*64 + l16) * 32 + lg*8);
  #pragma unroll 2
  for (int q = ks*101; q < ks*101 + 101; ++q){
    bf16x8 a0 = *reinterpret_cast<const bf16x8*>(arow0 + (long)q*32);
    bf16x8 a1 = *reinterpret_cast<const bf16x8*>(arow1 + (long)q*32);
    #pragma unroll
    for (int ns=0; ns<4; ++ns){
      bf16x8 b = *reinterpret_cast<const bf16x8*>(bb + ((long)q*512 + ns*16) * 32);
      acc[0][ns] = __builtin_amdgcn_mfma_f32_16x16x32_bf16(a0, b, acc[0][ns], 0,0,0);
      acc[1][ns] = __builtin_amdgcn_mfma_f32_16x16x32_bf16(a1, b, acc[1][ns], 0,0,0);
    }
  }
  #pragma unroll
  for (int ms=0; ms<2; ++ms)
    #pragma unroll
    for (int ns=0; ns<4; ++ns)
      #pragma unroll
      for (int r=0; r<4; ++r)
        part[((long)ks*1024 + m0 + ms*16 + lg*4 + r)*512 + wave*64 + ns*16 + l16] = acc[ms][ns][r];
}

__global__ void reduce_relu(const float* __restrict__ part, const float* __restrict__ b1,
                            float* __restrict__ d1)
{
  const int idx = blockIdx.x*256 + threadIdx.x;   // 524288 exact
  const int n = idx & 511, m = idx >> 9;
  float s = b1[n];
  #pragma unroll
  for (int k=0;k<8;k++) s += part[((long)k*1024 + m)*512 + n];
  d1[idx] = fmaxf(s, 0.f);
}

// ---- MLP layers 2..4 fused, one block per batch row ----
__launch_bounds__(128)
__global__ void mlp_tail(const float* __restrict__ d1, const float* __restrict__ W2T,
                         const float* __restrict__ b2, const float* __restrict__ W3T,
                         const float* __restrict__ b3, const float* __restrict__ Wout,
                         const float* __restrict__ bout, float* __restrict__ tag)
{
  __shared__ float r1[512];
  __shared__ float r2[128];
  __shared__ float r3[64];
  const int b = blockIdx.x;
  const int tid = threadIdx.x;
  for (int i = tid; i < 512; i += 128) r1[i] = d1[(long)b*512 + i];
  __syncthreads();
  float a = b2[tid];
  #pragma unroll 8
  for (int k=0;k<512;++k) a += W2T[k*128 + tid] * r1[k];
  r2[tid] = fmaxf(a, 0.f);
  __syncthreads();
  if (tid < 64){
    float a3 = b3[tid];
    #pragma unroll 8
    for (int k=0;k<128;++k) a3 += W3T[k*64 + tid] * r2[k];
    r3[tid] = fmaxf(a3, 0.f);
  }
  __syncthreads();
  if (tid < 64){
    float p = r3[tid] * Wout[tid];
    #pragma unroll
    for (int off=1; off<64; off<<=1) p += __shfl_xor(p, off);
    if (tid == 0) tag[b] = p + bout[0];
  }
}

extern "C" void kernel_launch(void* const* d_in, const int* in_sizes, int n_in,
                              void* d_out, int out_size, void* d_ws, size_t ws_size,
                              hipStream_t stream)
{
  const int*   ids   = (const int*)  d_in[0];
  const float* emb   = (const float*)d_in[1];
  const float* Wih1  = (const float*)d_in[2];
  const float* Whh1  = (const float*)d_in[3];
  const float* bih1  = (const float*)d_in[4];
  const float* bhh1  = (const float*)d_in[5];
  const float* Wih2  = (const float*)d_in[6];
  const float* Whh2  = (const float*)d_in[7];
  const float* bih2  = (const float*)d_in[8];
  const float* bhh2  = (const float*)d_in[9];
  const float* Wattn = (const float*)d_in[10];
  const float* battn = (const float*)d_in[11];
  const float* W1    = (const float*)d_in[12];
  const float* b1    = (const float*)d_in[13];
  const float* W2    = (const float*)d_in[14];
  const float* b2    = (const float*)d_in[15];
  const float* W3    = (const float*)d_in[16];
  const float* b3    = (const float*)d_in[17];
  const float* Wout  = (const float*)d_in[18];
  const float* bout  = (const float*)d_in[19];
  float* out = (float*)d_out;
  char*  ws  = (char*)d_ws;

  // workspace layout (bytes)
  constexpr size_t OW_IH1 = 0;
  constexpr size_t OW_HH1 = 524288;
  constexpr size_t OW_IH2 = 1048576;
  constexpr size_t OW_HH2 = 1572864;
  constexpr size_t OW_ATT = 2097152;     // 13,238,272
  constexpr size_t OW_W1  = 15335424;    // 26,476,544
  constexpr size_t OW_W2T = 41811968;
  constexpr size_t OW_W3T = 42074112;
  constexpr size_t OB1    = 42106880;
  constexpr size_t OB2    = 42110976;
  constexpr size_t OXH2   = 42115072;    // x bf16, later h2 (alias)
  constexpr size_t OG     = 94248960;    // FLAT + PART region
  constexpr size_t OFLAT  = OG;
  constexpr size_t OPART  = OG + 52953088;
  constexpr size_t OH1    = 302784512;
  constexpr size_t OD1    = 354918400;   // d1 (2MB) — dead during LSTMs:
  constexpr size_t OHX    = OD1;         //   hX: 2 parity x 63 x 8KB = 1,032,192
  constexpr size_t OFLG   = OD1 + 1032192; // flags: 2 layers x 4KB
  constexpr size_t NEED   = 357015552;
  if (ws_size < NEED) return;

  bf16*  pIH1 = (bf16*) (ws + OW_IH1);
  bf16*  pHH1 = (bf16*) (ws + OW_HH1);
  bf16*  pIH2 = (bf16*) (ws + OW_IH2);
  bf16*  pHH2 = (bf16*) (ws + OW_HH2);
  bf16*  pATT = (bf16*) (ws + OW_ATT);
  bf16*  pW1  = (bf16*) (ws + OW_W1);
  float* pW2T = (float*)(ws + OW_W2T);
  float* pW3T = (float*)(ws + OW_W3T);
  float* pB1  = (float*)(ws + OB1);
  float* pB2  = (float*)(ws + OB2);
  bf16*  pXH2 = (bf16*) (ws + OXH2);
  bf16*  pFLAT= (bf16*) (ws + OFLAT);
  float* pPART= (float*)(ws + OPART);
  bf16*  pH1  = (bf16*) (ws + OH1);
  float* pD1  = (float*)(ws + OD1);
  unsigned* pHX  = (unsigned*)(ws + OHX);
  unsigned* pFL1 = (unsigned*)(ws + OFLG);
  unsigned* pFL2 = (unsigned*)(ws + OFLG + 4096);

  // zero exchange flags for both LSTM layers (graph-replay safe)
  hipMemsetAsync(ws + OFLG, 0, 8192, stream);

  // weight packing
  pack_bT<<<dim3(128),        256, 0, stream>>>(Wih1,  pIH1, 1024, 256);
  pack_bT<<<dim3(128),        256, 0, stream>>>(Whh1,  pHH1, 1024, 256);
  pack_bT<<<dim3(128),        256, 0, stream>>>(Wih2,  pIH2, 1024, 256);
  pack_bT<<<dim3(128),        256, 0, stream>>>(Whh2,  pHH2, 1024, 256);
  pack_bT<<<dim3(32, 101),    256, 0, stream>>>(Wattn, pATT, 256,  256);
  pack_bT<<<dim3(6464),       256, 0, stream>>>(W1,    pW1,  512,  25856);
  tr_f32 <<<dim3(256),        256, 0, stream>>>(W2, pW2T, 128, 512);
  tr_f32 <<<dim3(32),         256, 0, stream>>>(W3, pW3T, 64, 128);
  bias_sum<<<dim3(4),         256, 0, stream>>>(bih1, bhh1, pB1, 1024);
  bias_sum<<<dim3(4),         256, 0, stream>>>(bih2, bhh2, pB2, 1024);

  // embed -> x bf16
  embed_k<<<dim3(12728), 256, 0, stream>>>(ids, emb, pXH2);

  // fused LSTM layers (gates GEMM folded in)
  lstm_fused<<<dim3(252), 512, 0, stream>>>(pXH2, pIH1, pHH1, pB1, pH1,  pHX, pFL1);
  lstm_fused<<<dim3(252), 512, 0, stream>>>(pH1,  pIH2, pHH2, pB2, pXH2, pHX, pFL2);

  // flat pad rows [1000,1024) zero
  hipMemsetAsync(ws + OFLAT + (size_t)B_*25856*2, 0, (size_t)24*25856*2, stream);

  // attention + softmax + applied (writes d_out applied region + flat bf16)
  attn_applied<<<dim3(32, 101), 256, 0, stream>>>(pXH2, pATT, battn, ids, emb,
                                                  out + 1000, pFLAT);

  // MLP
  gemm_mlp1  <<<dim3(32, 8), 512, 0, stream>>>(pFLAT, pW1, pPART);
  reduce_relu<<<dim3(2048),  256, 0, stream>>>(pPART, b1, pD1);
  mlp_tail   <<<dim3(1000),  128, 0, stream>>>(pD1, pW2T, b2, pW3T, b3, Wout, bout, out);
}